// Round 2
// baseline (281.186 us; speedup 1.0000x reference)
//
#include <hip/hip_runtime.h>
#include <math.h>

// ---------------------------------------------------------------------------
// TransformerBlock on MI355X (gfx950).  B=4, N=2048, C=512, H=8, D=64.
// All matmuls bf16 MFMA 16x16x32, fp32 accumulate. Residuals fp32.
// R9: k_attn is LDS-BW-bound (28 b128 reads/wave/kt ~ 6.9k cyc/CU/kt vs
//     7.9k wall; MfmaUtil 25 / VALU 32 / HBM 11 all low). Hoist V fragments
//     out of the nt loop (16->8 reads, total 28->20) into vf[2][4] regs;
//     s_setprio(1) around MFMA clusters (T5, +4-7% on attn per m191).
// ---------------------------------------------------------------------------

using bf16x8 = __attribute__((ext_vector_type(8))) short;
using f32x4  = __attribute__((ext_vector_type(4))) float;

typedef unsigned short u16;
typedef unsigned int   u32;

__device__ __forceinline__ u16 f2bf(float f) {
    u32 u; __builtin_memcpy(&u, &f, 4);
    u32 r = u + 0x7FFFu + ((u >> 16) & 1u);   // RNE
    return (u16)(r >> 16);
}
__device__ __forceinline__ u32 fbits(float f) {
    u32 u; __builtin_memcpy(&u, &f, 4); return u;
}
__device__ __forceinline__ float f_from_bits(u32 u) {
    float f; __builtin_memcpy(&f, &u, 4); return f;
}
// pack two f32 -> two bf16 (truncation) in ONE v_perm_b32
__device__ __forceinline__ u32 pack_trunc(float lo, float hi) {
    return __builtin_amdgcn_perm(fbits(hi), fbits(lo), 0x07060302u);
}
// async global->LDS, 16B per lane; LDS dest = wave-uniform base + lane*16
__device__ __forceinline__ void gload16(const void* g, void* l) {
    __builtin_amdgcn_global_load_lds(
        (const __attribute__((address_space(1))) unsigned int*)g,
        (__attribute__((address_space(3))) unsigned int*)l, 16, 0, 0);
}

// ---------------------------------------------------------------------------
// Fused preprocessing: blocks 0..3071 = weight cast+transpose (4 weights),
// blocks 3072..5119 = LayerNorm1 (fp32 x -> bf16 h).
// ---------------------------------------------------------------------------
__global__ __launch_bounds__(256) void k_pre(
        const float* __restrict__ w0, u16* __restrict__ d0,   // 512x1536
        const float* __restrict__ w1, u16* __restrict__ d1,   // 512x512
        const float* __restrict__ w2, u16* __restrict__ d2,   // 512x2048
        const float* __restrict__ w3, u16* __restrict__ d3,   // 2048x512
        const float* __restrict__ x, const float* __restrict__ g,
        const float* __restrict__ bta, u16* __restrict__ hout) {
    __shared__ float tile[32][33];
    const int bid = blockIdx.x;
    if (bid < 3072) {
        const float* w; u16* dst; int K, N, tb;
        if (bid < 768)       { w = w0; dst = d0; K = 512;  N = 1536; tb = bid; }
        else if (bid < 1024) { w = w1; dst = d1; K = 512;  N = 512;  tb = bid - 768; }
        else if (bid < 2048) { w = w2; dst = d2; K = 512;  N = 2048; tb = bid - 1024; }
        else                 { w = w3; dst = d3; K = 2048; N = 512;  tb = bid - 2048; }
        const int nb = N >> 5;
        const int k0 = (tb / nb) << 5;
        const int n0 = (tb % nb) << 5;
        const int c = threadIdx.x & 31, r = threadIdx.x >> 5;
#pragma unroll
        for (int i = 0; i < 4; i++)
            tile[r + i * 8][c] = w[(size_t)(k0 + r + i * 8) * N + n0 + c];
        __syncthreads();
#pragma unroll
        for (int i = 0; i < 4; i++)
            dst[(size_t)(n0 + r + i * 8) * K + k0 + c] = f2bf(tile[c][r + i * 8]);
    } else {
        const int row  = ((bid - 3072) << 2) + (threadIdx.x >> 6);
        const int lane = threadIdx.x & 63;
        const float* xr = x + (size_t)row * 512 + lane * 8;
        float4 a = *(const float4*)xr;
        float4 c = *(const float4*)(xr + 4);
        float s = a.x + a.y + a.z + a.w + c.x + c.y + c.z + c.w;
        float q = a.x*a.x + a.y*a.y + a.z*a.z + a.w*a.w
                + c.x*c.x + c.y*c.y + c.z*c.z + c.w*c.w;
#pragma unroll
        for (int off = 32; off; off >>= 1) {
            s += __shfl_xor(s, off, 64);
            q += __shfl_xor(q, off, 64);
        }
        const float mean = s * (1.0f / 512.0f);
        const float var  = q * (1.0f / 512.0f) - mean * mean;
        const float rstd = rsqrtf(var + 1e-5f);
        float vv[8] = {a.x, a.y, a.z, a.w, c.x, c.y, c.z, c.w};
#pragma unroll
        for (int j = 0; j < 8; j++) {
            const int col = lane * 8 + j;
            hout[(size_t)row * 512 + col] = f2bf((vv[j] - mean) * rstd * g[col] + bta[col]);
        }
    }
}

// ---------------------------------------------------------------------------
// LayerNorm fp32 -> bf16 (standalone, for LN2).
// ---------------------------------------------------------------------------
__global__ __launch_bounds__(256) void k_ln(const float* __restrict__ x,
                                            const float* __restrict__ g,
                                            const float* __restrict__ bta,
                                            u16* __restrict__ out) {
    const int row  = (blockIdx.x << 2) + (threadIdx.x >> 6);
    const int lane = threadIdx.x & 63;
    const float* xr = x + (size_t)row * 512 + lane * 8;
    float4 a = *(const float4*)xr;
    float4 c = *(const float4*)(xr + 4);
    float s = a.x + a.y + a.z + a.w + c.x + c.y + c.z + c.w;
    float q = a.x*a.x + a.y*a.y + a.z*a.z + a.w*a.w
            + c.x*c.x + c.y*c.y + c.z*c.z + c.w*c.w;
#pragma unroll
    for (int off = 32; off; off >>= 1) {
        s += __shfl_xor(s, off, 64);
        q += __shfl_xor(q, off, 64);
    }
    const float mean = s * (1.0f / 512.0f);
    const float var  = q * (1.0f / 512.0f) - mean * mean;
    const float rstd = rsqrtf(var + 1e-5f);
    float vv[8] = {a.x, a.y, a.z, a.w, c.x, c.y, c.z, c.w};
#pragma unroll
    for (int j = 0; j < 8; j++) {
        const int col = lane * 8 + j;
        out[(size_t)row * 512 + col] = f2bf((vv[j] - mean) * rstd * g[col] + bta[col]);
    }
}

// ---------------------------------------------------------------------------
// GEMM: C[M,N] = A[M,K](bf16) @ Bt[N,K]^T + bias. m97 staging, BK=64,
// 128xTN tile. XCD-grouped decode: xcd = bid&7 owns m-rows m%8==xcd ->
// A-tiles fetched by exactly one XCD; B (<=2MB) L2-resident per XCD.
// EP=1: +tanh-GELU -> bf16.  EP=2: +fp32 residual -> fp32.
// EP=3: QKV — Q cols (<512) pre-scaled by 0.125*log2e, V cols -> vt transposed.
// 8-chunk XOR swizzle (chunk ^= row&7): b128 reads 2-way (free).
// ---------------------------------------------------------------------------
template <int EP, int TN>
__global__ __launch_bounds__(256, 3) void k_gemm(const u16* __restrict__ A,
                                                 const u16* __restrict__ Bt,
                                                 const float* __restrict__ bias,
                                                 const float* __restrict__ res,
                                                 float* __restrict__ outF,
                                                 u16* __restrict__ outB,
                                                 u16* __restrict__ out2,
                                                 int M, int N, int K) {
    constexpr int NT = TN / 32;
    __shared__ u16 As[128 * 64];
    __shared__ u16 Bs[TN * 64];
    const int nb = N / TN;
    // XCD-grouped block decode (grid = (M/128)*nb, M/128 divisible by 8):
    // x = bid&7 -> XCD; within XCD: n fastest (B cycles, L2-resident),
    // m-group slowest (A-tile hot across nb consecutive slots).
    const int xg = blockIdx.x & 7, sg = blockIdx.x >> 3;
    const int m0 = ((sg / nb) * 8 + xg) << 7;
    const int n0 = (sg % nb) * TN;
    const int t = threadIdx.x, lane = t & 63, w = t >> 6;
    const int wr = (w >> 1) << 6;
    const int wc = (w & 1) * (TN / 2);
    const int quad = lane >> 4, l15 = lane & 15;
    const int x7 = l15 & 7;

    f32x4 acc[4][NT];
#pragma unroll
    for (int i = 0; i < 4; i++)
#pragma unroll
        for (int j = 0; j < NT; j++) acc[i][j] = (f32x4){0.f, 0.f, 0.f, 0.f};

    const size_t Kb = (size_t)K * 2;
    const char* ga = (const char*)A + (size_t)m0 * Kb;
    const char* gb = (const char*)Bt + (size_t)n0 * Kb;
    const int o0 = t * 16;

    for (int k0 = 0; k0 < K; k0 += 64) {
        const int kb = k0 * 2;
#pragma unroll
        for (int i = 0; i < 4; i++) {              // A: 128 rows x 128B
            const int o4 = i * 4096 + o0;
            const int row = o4 >> 7;
            const int lc = ((o4 >> 4) & 7) ^ (row & 7);
            gload16(ga + (size_t)row * Kb + kb + lc * 16, (char*)As + o4);
        }
#pragma unroll
        for (int i = 0; i < TN / 32; i++) {        // B: TN rows x 128B
            const int o4 = i * 4096 + o0;
            const int row = o4 >> 7;
            const int lc = ((o4 >> 4) & 7) ^ (row & 7);
            gload16(gb + (size_t)row * Kb + kb + lc * 16, (char*)Bs + o4);
        }
        __syncthreads();
#pragma unroll
        for (int ks = 0; ks < 2; ks++) {
            const int cidx = ((ks * 4 + quad) ^ x7) * 8;
            bf16x8 af[4], bfr[NT];
#pragma unroll
            for (int i = 0; i < 4; i++)
                af[i] = *(const bf16x8*)(As + (wr + i * 16 + l15) * 64 + cidx);
#pragma unroll
            for (int j = 0; j < NT; j++)
                bfr[j] = *(const bf16x8*)(Bs + (wc + j * 16 + l15) * 64 + cidx);
#pragma unroll
            for (int mt = 0; mt < 4; mt++)
#pragma unroll
                for (int nt = 0; nt < NT; nt++)
                    acc[mt][nt] = __builtin_amdgcn_mfma_f32_16x16x32_bf16(
                        af[mt], bfr[nt], acc[mt][nt], 0, 0, 0);
        }
        __syncthreads();
    }

    const bool vpart = (EP == 3) && (n0 >= 1024);          // block-uniform
    const bool qpart = (EP == 3) && (n0 < 512);            // block-uniform
#pragma unroll
    for (int mt = 0; mt < 4; mt++)
#pragma unroll
        for (int nt = 0; nt < NT; nt++) {
            const int col = n0 + wc + nt * 16 + l15;
            const float bi = bias[col];
            const int row0 = m0 + wr + mt * 16 + quad * 4;
            if (vpart) {
                const int b = row0 >> 11, key = row0 & 2047;
                const int hd = col - 1024;          // h*64 + d
                u32 p0 = (u32)f2bf(acc[mt][nt][0] + bi) |
                         ((u32)f2bf(acc[mt][nt][1] + bi) << 16);
                u32 p1 = (u32)f2bf(acc[mt][nt][2] + bi) |
                         ((u32)f2bf(acc[mt][nt][3] + bi) << 16);
                *(uint2*)(out2 + (size_t)(b * 512 + hd) * 2048 + key) = make_uint2(p0, p1);
            } else {
#pragma unroll
                for (int r = 0; r < 4; r++) {
                    const int row = row0 + r;
                    float v = acc[mt][nt][r] + bi;
                    const size_t oi = (size_t)row * N + col;
                    if (EP == 1) {
                        float y = v * (0.79788456f + 0.035677408f * v * v);
                        y = fminf(y, 40.0f);
                        float tE = exp2f(y * 2.88539008f);
                        v = v * tE * __builtin_amdgcn_rcpf(tE + 1.0f);
                    }
                    if (qpart) v *= 0.18033688f;    // 0.125*log2(e) for attn exp2
                    if (EP == 2) outF[oi] = v + res[oi];
                    else         outB[oi] = f2bf(v);
                }
            }
        }
}

// ---------------------------------------------------------------------------
// Flash attention, transposed + max-free, key-split 2x, q-tile 128.
// Double-buffered K/V (2x16KB) + 2KB/wave P bounce = 40KB LDS, 4 blk/CU.
// Per kt: __syncthreads (drains PREVIOUS prefetch via its vmcnt(0)) ->
// issue kt+1 staging into other buffer -> QK^T -> hoisted V frags (once) ->
// per-nt {exp, P write/read (wave-private), PV}. LDS reads/wave/kt: 8 K +
// 8 V + 4 P = 20 b128 (was 28: V was re-read per nt). setprio around MFMA.
// XCD-aware decode: xcd = bid&7 = head h; per-XCD working set ~3MB < L2.
// ---------------------------------------------------------------------------
__global__ __launch_bounds__(256, 4) void k_attn(const u16* __restrict__ qkv,
                                                 const u16* __restrict__ vt,
                                                 u16* __restrict__ po0,
                                                 u16* __restrict__ po1,
                                                 float* __restrict__ pden) {
    __shared__ u16 smem[20480];              // 40 KB
    // bytes: [0,8K) Ks0 | [8K,16K) Vs0 | [16K,24K) Ks1 | [24K,32K) Vs1
    //        [32K,40K) P (2KB per wave, wave-private)
    const int bid = blockIdx.x;
    const int h = bid & 7, sg = bid >> 3;
    const int qt = sg & 15, kh = (sg >> 4) & 1, b = sg >> 5;
    const int q0 = qt << 7;
    const int t = threadIdx.x, lane = t & 63, w = t >> 6;
    const int quad = lane >> 4, l15 = lane & 15;
    const int x7 = l15 & 7;

    char* sb = (char*)smem;
    const char* gk = (const char*)qkv + (size_t)((b << 11) + (kh << 10)) * 3072 + 1024 + h * 128;
    const char* gv = (const char*)vt + (size_t)((b << 3) + h) * 64 * 4096 + (kh << 10) * 2;

    // ---- prologue: prefetch K/V tile 0 into buf0 (drained at first sync) ----
#pragma unroll
    for (int i = 0; i < 2; i++) {
        const int o4 = i * 4096 + t * 16;
        const int row = o4 >> 7;
        const int lc = ((o4 >> 4) & 7) ^ (row & 7);
        gload16(gk + (size_t)row * 3072 + lc * 16, sb + o4);
        gload16(gv + (size_t)row * 4096 + lc * 16, sb + 8192 + o4);
    }

    // ---- Q fragments straight from global (loop-invariant, 16B segments) ----
    bf16x8 qf[2][2];
    {
        const u16* gqp = qkv + (size_t)((b << 11) + q0 + w * 32 + l15) * 1536 + h * 64;
#pragma unroll
        for (int ks = 0; ks < 2; ks++)
#pragma unroll
            for (int nt = 0; nt < 2; nt++)
                qf[ks][nt] = *(const bf16x8*)(gqp + (size_t)(nt * 16) * 1536 + (ks * 4 + quad) * 8);
    }

    f32x4 accO[4][2];
    float denp[2] = {0.f, 0.f};
#pragma unroll
    for (int mt = 0; mt < 4; mt++)
#pragma unroll
        for (int nt = 0; nt < 2; nt++) accO[mt][nt] = (f32x4){0.f, 0.f, 0.f, 0.f};

    u16* Pw = smem + 16384 + w * 1024;       // 16 q-rows x 64 keys, this wave only

    for (int kt = 0; kt < 16; kt++) {
        const int cur = kt & 1;
        // drains own outstanding staging loads (vmcnt(0)) + barrier:
        // tile kt (issued one iteration ago) is now visible to all waves.
        __syncthreads();
        if (kt < 15) {                       // prefetch tile kt+1 into other buf
            const int kk2 = (kt + 1) << 6;
            char* db = sb + (cur ^ 1) * 16384;
#pragma unroll
            for (int i = 0; i < 2; i++) {
                const int o4 = i * 4096 + t * 16;
                const int row = o4 >> 7;
                const int lc = ((o4 >> 4) & 7) ^ (row & 7);
                gload16(gk + (size_t)(kk2 + row) * 3072 + lc * 16, db + o4);
                gload16(gv + (size_t)row * 4096 + (size_t)kk2 * 2 + lc * 16, db + 8192 + o4);
            }
        }
        const u16* Ksc = smem + cur * 8192;
        const u16* Vsc = Ksc + 4096;

        // S^T = K Q^T
        f32x4 s[4][2];
#pragma unroll
        for (int mt = 0; mt < 4; mt++)
#pragma unroll
            for (int nt = 0; nt < 2; nt++) s[mt][nt] = (f32x4){0.f, 0.f, 0.f, 0.f};
#pragma unroll
        for (int ks = 0; ks < 2; ks++) {
            const int cidx = ((ks * 4 + quad) ^ x7) * 8;
            bf16x8 kf[4];
#pragma unroll
            for (int mt = 0; mt < 4; mt++)
                kf[mt] = *(const bf16x8*)(Ksc + (mt * 16 + l15) * 64 + cidx);
            __builtin_amdgcn_s_setprio(1);
#pragma unroll
            for (int mt = 0; mt < 4; mt++)
#pragma unroll
                for (int nt = 0; nt < 2; nt++)
                    s[mt][nt] = __builtin_amdgcn_mfma_f32_16x16x32_bf16(
                        kf[mt], qf[ks][nt], s[mt][nt], 0, 0, 0);
            __builtin_amdgcn_s_setprio(0);
        }

        // V fragments: read ONCE per kt (reused by both nt) — 8 b128
        bf16x8 vf[2][4];
#pragma unroll
        for (int ks = 0; ks < 2; ks++) {
            const int cidx = ((ks * 4 + quad) ^ x7) * 8;
#pragma unroll
            for (int mt = 0; mt < 4; mt++)
                vf[ks][mt] = *(const bf16x8*)(Vsc + (mt * 16 + l15) * 64 + cidx);
        }

        // per 16-q group: p = exp2(s) -> P^T rows (wave-private) -> O^T += V^T P^T
#pragma unroll
        for (int nt = 0; nt < 2; nt++) {
#pragma unroll
            for (int mt = 0; mt < 4; mt++) {
                const float p0 = __builtin_amdgcn_exp2f(s[mt][nt][0]);
                const float p1 = __builtin_amdgcn_exp2f(s[mt][nt][1]);
                const float p2 = __builtin_amdgcn_exp2f(s[mt][nt][2]);
                const float p3 = __builtin_amdgcn_exp2f(s[mt][nt][3]);
                denp[nt] += (p0 + p1) + (p2 + p3);
                const u32 d0 = pack_trunc(p0, p1);
                const u32 d1 = pack_trunc(p2, p3);
                const int pidx = l15 * 64 +
                                 (((2 * mt + (quad >> 1)) ^ x7) << 3) + (quad & 1) * 4;
                *(uint2*)(&Pw[pidx]) = make_uint2(d0, d1);
            }
#pragma unroll
            for (int ks = 0; ks < 2; ks++) {
                const int cidx = ((ks * 4 + quad) ^ x7) * 8;
                const bf16x8 pf = *(const bf16x8*)(Pw + l15 * 64 + cidx);
                __builtin_amdgcn_s_setprio(1);
#pragma unroll
                for (int mt = 0; mt < 4; mt++)
                    accO[mt][nt] = __builtin_amdgcn_mfma_f32_16x16x32_bf16(
                        vf[ks][mt], pf, accO[mt][nt], 0, 0, 0);
                __builtin_amdgcn_s_setprio(0);
            }
        }
    }

    // epilogue: partial den (quad-reduced) + raw partial O (bf16)
    u16* po = kh ? po1 : po0;
#pragma unroll
    for (int nt = 0; nt < 2; nt++) {
        float dn = denp[nt];
        dn += __shfl_xor(dn, 16, 64);
        dn += __shfl_xor(dn, 32, 64);
        if (quad == 0)
            pden[(size_t)(((kh << 5) + (b << 3) + h) << 11) + q0 + w * 32 + nt * 16 + l15] = dn;
#pragma unroll
        for (int mt = 0; mt < 4; mt++) {
            const int qg = q0 + w * 32 + nt * 16 + l15;
            const u32 p0 = (u32)f2bf(accO[mt][nt][0]) | ((u32)f2bf(accO[mt][nt][1]) << 16);
            const u32 p1 = (u32)f2bf(accO[mt][nt][2]) | ((u32)f2bf(accO[mt][nt][3]) << 16);
            *(uint2*)(po + (size_t)((b << 11) + qg) * 512 + h * 64 + mt * 16 + quad * 4) =
                make_uint2(p0, p1);
        }
    }
}

// ---------------------------------------------------------------------------
// Combine: o = (po0 + po1) / (den0 + den1), in-place over po0.
// ---------------------------------------------------------------------------
__global__ __launch_bounds__(256) void k_combine(u16* __restrict__ po0,
                                                 const u16* __restrict__ po1,
                                                 const float* __restrict__ pden) {
    const int idx8 = (blockIdx.x * 256 + threadIdx.x) * 8;
    const int row = idx8 >> 9, col = idx8 & 511;
    const int h = col >> 6, q = row & 2047, b = row >> 11;
    const size_t di = (size_t)(((b << 3) + h) << 11) + q;
    const float den = pden[di] + pden[di + (32 << 11)];
    const float r = __builtin_amdgcn_rcpf(den);
    uint4 a = *(const uint4*)(po0 + idx8);
    uint4 c = *(const uint4*)(po1 + idx8);
    u32 av[4] = {a.x, a.y, a.z, a.w}, cv[4] = {c.x, c.y, c.z, c.w}, ov[4];
#pragma unroll
    for (int i = 0; i < 4; i++) {
        const float lo = (f_from_bits(av[i] << 16) + f_from_bits(cv[i] << 16)) * r;
        const float hi = (f_from_bits(av[i] & 0xFFFF0000u) +
                          f_from_bits(cv[i] & 0xFFFF0000u)) * r;
        ov[i] = (u32)f2bf(lo) | ((u32)f2bf(hi) << 16);
    }
    *(uint4*)(po0 + idx8) = make_uint4(ov[0], ov[1], ov[2], ov[3]);
}

// ---------------------------------------------------------------------------
// Host-side pipeline.
// ---------------------------------------------------------------------------
extern "C" void kernel_launch(void* const* d_in, const int* in_sizes, int n_in,
                              void* d_out, int out_size, void* d_ws, size_t ws_size,
                              hipStream_t stream) {
    const float* x      = (const float*)d_in[0];
    const float* ln1_g  = (const float*)d_in[1];
    const float* ln1_b  = (const float*)d_in[2];
    const float* qkv_w  = (const float*)d_in[3];
    const float* qkv_b  = (const float*)d_in[4];
    const float* proj_w = (const float*)d_in[5];
    const float* proj_b = (const float*)d_in[6];
    const float* ln2_g  = (const float*)d_in[7];
    const float* ln2_b  = (const float*)d_in[8];
    const float* fc1_w  = (const float*)d_in[9];
    const float* fc1_b  = (const float*)d_in[10];
    const float* fc2_w  = (const float*)d_in[11];
    const float* fc2_b  = (const float*)d_in[12];
    float* out = (float*)d_out;
    char* ws = (char*)d_ws;

    u16*   qkv_wT = (u16*)(ws + 0);          // 1536x512  bf16
    u16*   proj_wT= (u16*)(ws + 1572864);    // 512x512
    u16*   fc1_wT = (u16*)(ws + 2097152);    // 2048x512
    u16*   fc2_wT = (u16*)(ws + 4194304);    // 512x2048
    u16*   h      = (u16*)(ws + 6291456);    // 8192x512 bf16 (LN outs)
    float* pden   = (float*)(ws + 6291456);  // 512KB, aliases h (dead in attn window)
    u16*   qkv    = (u16*)(ws + 14680064);   // 8192x1536
    u16*   vt     = (u16*)(ws + 39845888);   // [b*8+h][64 d][2048 key]
    u16*   o      = (u16*)(ws + 48234496);   // 8192x512 (= po0, combined in-place)
    u16*   po1    = (u16*)(ws + 56623104);   // aliases x1 (dead until proj)
    float* x1     = (float*)(ws + 56623104); // 8192x512 fp32
    u16*   f1     = (u16*)(ws + 14680064);   // 8192x2048 (reuse qkv+vt)
    u16*   h2     = h;

    // weights cast+T  +  LN1, one launch
    k_pre<<<5120, 256, 0, stream>>>(qkv_w, qkv_wT, proj_w, proj_wT,
                                    fc1_w, fc1_wT, fc2_w, fc2_wT,
                                    x, ln1_g, ln1_b, h);
    // QKV GEMM; Q cols pre-scaled, V cols -> vt transposed
    k_gemm<3,128><<<(8192/128)*(1536/128), 256, 0, stream>>>(
        h, qkv_wT, qkv_b, nullptr, nullptr, qkv, vt, 8192, 1536, 512);
    // attention, key-split 2x -> partials
    k_attn<<<1024, 256, 0, stream>>>(qkv, vt, o, po1, pden);
    k_combine<<<2048, 256, 0, stream>>>(o, po1, pden);
    // proj GEMM + residual(x) -> x1 fp32
    k_gemm<2,64><<<(8192/128)*(512/64), 256, 0, stream>>>(
        o, proj_wT, proj_b, x, x1, nullptr, nullptr, 8192, 512, 512);
    k_ln<<<2048, 256, 0, stream>>>(x1, ln2_g, ln2_b, h2);
    // FC1 + GELU
    k_gemm<1,128><<<(8192/128)*(2048/128), 256, 0, stream>>>(
        h2, fc1_wT, fc1_b, nullptr, nullptr, f1, nullptr, 8192, 2048, 512);
    // FC2 + residual(x1) -> out fp32
    k_gemm<2,64><<<(8192/128)*(512/64), 256, 0, stream>>>(
        f1, fc2_wT, fc2_b, x1, out, nullptr, nullptr, 8192, 512, 2048);
}

// Round 3
// 244.277 us; speedup vs baseline: 1.1511x; 1.1511x over previous
//
#include <hip/hip_runtime.h>
#include <math.h>

// ---------------------------------------------------------------------------
// TransformerBlock on MI355X (gfx950).  B=4, N=2048, C=512, H=8, D=64.
// All matmuls bf16 MFMA 16x16x32, fp32 accumulate. Residuals fp32.
// R10: R9's V-hoist spilled (FETCH 15->71MB = scratch traffic): vf[2][4]
//      (+32 VGPR) overlapped live s[4][2] (32) -> ~160 > 128-reg cap.
//      Fix: exp2+pack S->P registers (pp, 16 u32) IMMEDIATELY after QK^T so
//      s dies before V loads; sched_barrier(0) pins the order. Peak live
//      ~116 regs < 128. LDS reads stay 20 b128/wave/kt (28 in R8).
// ---------------------------------------------------------------------------

using bf16x8 = __attribute__((ext_vector_type(8))) short;
using f32x4  = __attribute__((ext_vector_type(4))) float;

typedef unsigned short u16;
typedef unsigned int   u32;

__device__ __forceinline__ u16 f2bf(float f) {
    u32 u; __builtin_memcpy(&u, &f, 4);
    u32 r = u + 0x7FFFu + ((u >> 16) & 1u);   // RNE
    return (u16)(r >> 16);
}
__device__ __forceinline__ u32 fbits(float f) {
    u32 u; __builtin_memcpy(&u, &f, 4); return u;
}
__device__ __forceinline__ float f_from_bits(u32 u) {
    float f; __builtin_memcpy(&f, &u, 4); return f;
}
// pack two f32 -> two bf16 (truncation) in ONE v_perm_b32
__device__ __forceinline__ u32 pack_trunc(float lo, float hi) {
    return __builtin_amdgcn_perm(fbits(hi), fbits(lo), 0x07060302u);
}
// async global->LDS, 16B per lane; LDS dest = wave-uniform base + lane*16
__device__ __forceinline__ void gload16(const void* g, void* l) {
    __builtin_amdgcn_global_load_lds(
        (const __attribute__((address_space(1))) unsigned int*)g,
        (__attribute__((address_space(3))) unsigned int*)l, 16, 0, 0);
}

// ---------------------------------------------------------------------------
// Fused preprocessing: blocks 0..3071 = weight cast+transpose (4 weights),
// blocks 3072..5119 = LayerNorm1 (fp32 x -> bf16 h).
// ---------------------------------------------------------------------------
__global__ __launch_bounds__(256) void k_pre(
        const float* __restrict__ w0, u16* __restrict__ d0,   // 512x1536
        const float* __restrict__ w1, u16* __restrict__ d1,   // 512x512
        const float* __restrict__ w2, u16* __restrict__ d2,   // 512x2048
        const float* __restrict__ w3, u16* __restrict__ d3,   // 2048x512
        const float* __restrict__ x, const float* __restrict__ g,
        const float* __restrict__ bta, u16* __restrict__ hout) {
    __shared__ float tile[32][33];
    const int bid = blockIdx.x;
    if (bid < 3072) {
        const float* w; u16* dst; int K, N, tb;
        if (bid < 768)       { w = w0; dst = d0; K = 512;  N = 1536; tb = bid; }
        else if (bid < 1024) { w = w1; dst = d1; K = 512;  N = 512;  tb = bid - 768; }
        else if (bid < 2048) { w = w2; dst = d2; K = 512;  N = 2048; tb = bid - 1024; }
        else                 { w = w3; dst = d3; K = 2048; N = 512;  tb = bid - 2048; }
        const int nb = N >> 5;
        const int k0 = (tb / nb) << 5;
        const int n0 = (tb % nb) << 5;
        const int c = threadIdx.x & 31, r = threadIdx.x >> 5;
#pragma unroll
        for (int i = 0; i < 4; i++)
            tile[r + i * 8][c] = w[(size_t)(k0 + r + i * 8) * N + n0 + c];
        __syncthreads();
#pragma unroll
        for (int i = 0; i < 4; i++)
            dst[(size_t)(n0 + r + i * 8) * K + k0 + c] = f2bf(tile[c][r + i * 8]);
    } else {
        const int row  = ((bid - 3072) << 2) + (threadIdx.x >> 6);
        const int lane = threadIdx.x & 63;
        const float* xr = x + (size_t)row * 512 + lane * 8;
        float4 a = *(const float4*)xr;
        float4 c = *(const float4*)(xr + 4);
        float s = a.x + a.y + a.z + a.w + c.x + c.y + c.z + c.w;
        float q = a.x*a.x + a.y*a.y + a.z*a.z + a.w*a.w
                + c.x*c.x + c.y*c.y + c.z*c.z + c.w*c.w;
#pragma unroll
        for (int off = 32; off; off >>= 1) {
            s += __shfl_xor(s, off, 64);
            q += __shfl_xor(q, off, 64);
        }
        const float mean = s * (1.0f / 512.0f);
        const float var  = q * (1.0f / 512.0f) - mean * mean;
        const float rstd = rsqrtf(var + 1e-5f);
        float vv[8] = {a.x, a.y, a.z, a.w, c.x, c.y, c.z, c.w};
#pragma unroll
        for (int j = 0; j < 8; j++) {
            const int col = lane * 8 + j;
            hout[(size_t)row * 512 + col] = f2bf((vv[j] - mean) * rstd * g[col] + bta[col]);
        }
    }
}

// ---------------------------------------------------------------------------
// LayerNorm fp32 -> bf16 (standalone, for LN2).
// ---------------------------------------------------------------------------
__global__ __launch_bounds__(256) void k_ln(const float* __restrict__ x,
                                            const float* __restrict__ g,
                                            const float* __restrict__ bta,
                                            u16* __restrict__ out) {
    const int row  = (blockIdx.x << 2) + (threadIdx.x >> 6);
    const int lane = threadIdx.x & 63;
    const float* xr = x + (size_t)row * 512 + lane * 8;
    float4 a = *(const float4*)xr;
    float4 c = *(const float4*)(xr + 4);
    float s = a.x + a.y + a.z + a.w + c.x + c.y + c.z + c.w;
    float q = a.x*a.x + a.y*a.y + a.z*a.z + a.w*a.w
            + c.x*c.x + c.y*c.y + c.z*c.z + c.w*c.w;
#pragma unroll
    for (int off = 32; off; off >>= 1) {
        s += __shfl_xor(s, off, 64);
        q += __shfl_xor(q, off, 64);
    }
    const float mean = s * (1.0f / 512.0f);
    const float var  = q * (1.0f / 512.0f) - mean * mean;
    const float rstd = rsqrtf(var + 1e-5f);
    float vv[8] = {a.x, a.y, a.z, a.w, c.x, c.y, c.z, c.w};
#pragma unroll
    for (int j = 0; j < 8; j++) {
        const int col = lane * 8 + j;
        out[(size_t)row * 512 + col] = f2bf((vv[j] - mean) * rstd * g[col] + bta[col]);
    }
}

// ---------------------------------------------------------------------------
// GEMM: C[M,N] = A[M,K](bf16) @ Bt[N,K]^T + bias. m97 staging, BK=64,
// 128xTN tile. XCD-grouped decode: xcd = bid&7 owns m-rows m%8==xcd ->
// A-tiles fetched by exactly one XCD; B (<=2MB) L2-resident per XCD.
// EP=1: +tanh-GELU -> bf16.  EP=2: +fp32 residual -> fp32.
// EP=3: QKV — Q cols (<512) pre-scaled by 0.125*log2e, V cols -> vt transposed.
// 8-chunk XOR swizzle (chunk ^= row&7): b128 reads 2-way (free).
// ---------------------------------------------------------------------------
template <int EP, int TN>
__global__ __launch_bounds__(256, 3) void k_gemm(const u16* __restrict__ A,
                                                 const u16* __restrict__ Bt,
                                                 const float* __restrict__ bias,
                                                 const float* __restrict__ res,
                                                 float* __restrict__ outF,
                                                 u16* __restrict__ outB,
                                                 u16* __restrict__ out2,
                                                 int M, int N, int K) {
    constexpr int NT = TN / 32;
    __shared__ u16 As[128 * 64];
    __shared__ u16 Bs[TN * 64];
    const int nb = N / TN;
    // XCD-grouped block decode (grid = (M/128)*nb, M/128 divisible by 8):
    // x = bid&7 -> XCD; within XCD: n fastest (B cycles, L2-resident),
    // m-group slowest (A-tile hot across nb consecutive slots).
    const int xg = blockIdx.x & 7, sg = blockIdx.x >> 3;
    const int m0 = ((sg / nb) * 8 + xg) << 7;
    const int n0 = (sg % nb) * TN;
    const int t = threadIdx.x, lane = t & 63, w = t >> 6;
    const int wr = (w >> 1) << 6;
    const int wc = (w & 1) * (TN / 2);
    const int quad = lane >> 4, l15 = lane & 15;
    const int x7 = l15 & 7;

    f32x4 acc[4][NT];
#pragma unroll
    for (int i = 0; i < 4; i++)
#pragma unroll
        for (int j = 0; j < NT; j++) acc[i][j] = (f32x4){0.f, 0.f, 0.f, 0.f};

    const size_t Kb = (size_t)K * 2;
    const char* ga = (const char*)A + (size_t)m0 * Kb;
    const char* gb = (const char*)Bt + (size_t)n0 * Kb;
    const int o0 = t * 16;

    for (int k0 = 0; k0 < K; k0 += 64) {
        const int kb = k0 * 2;
#pragma unroll
        for (int i = 0; i < 4; i++) {              // A: 128 rows x 128B
            const int o4 = i * 4096 + o0;
            const int row = o4 >> 7;
            const int lc = ((o4 >> 4) & 7) ^ (row & 7);
            gload16(ga + (size_t)row * Kb + kb + lc * 16, (char*)As + o4);
        }
#pragma unroll
        for (int i = 0; i < TN / 32; i++) {        // B: TN rows x 128B
            const int o4 = i * 4096 + o0;
            const int row = o4 >> 7;
            const int lc = ((o4 >> 4) & 7) ^ (row & 7);
            gload16(gb + (size_t)row * Kb + kb + lc * 16, (char*)Bs + o4);
        }
        __syncthreads();
#pragma unroll
        for (int ks = 0; ks < 2; ks++) {
            const int cidx = ((ks * 4 + quad) ^ x7) * 8;
            bf16x8 af[4], bfr[NT];
#pragma unroll
            for (int i = 0; i < 4; i++)
                af[i] = *(const bf16x8*)(As + (wr + i * 16 + l15) * 64 + cidx);
#pragma unroll
            for (int j = 0; j < NT; j++)
                bfr[j] = *(const bf16x8*)(Bs + (wc + j * 16 + l15) * 64 + cidx);
#pragma unroll
            for (int mt = 0; mt < 4; mt++)
#pragma unroll
                for (int nt = 0; nt < NT; nt++)
                    acc[mt][nt] = __builtin_amdgcn_mfma_f32_16x16x32_bf16(
                        af[mt], bfr[nt], acc[mt][nt], 0, 0, 0);
        }
        __syncthreads();
    }

    const bool vpart = (EP == 3) && (n0 >= 1024);          // block-uniform
    const bool qpart = (EP == 3) && (n0 < 512);            // block-uniform
#pragma unroll
    for (int mt = 0; mt < 4; mt++)
#pragma unroll
        for (int nt = 0; nt < NT; nt++) {
            const int col = n0 + wc + nt * 16 + l15;
            const float bi = bias[col];
            const int row0 = m0 + wr + mt * 16 + quad * 4;
            if (vpart) {
                const int b = row0 >> 11, key = row0 & 2047;
                const int hd = col - 1024;          // h*64 + d
                u32 p0 = (u32)f2bf(acc[mt][nt][0] + bi) |
                         ((u32)f2bf(acc[mt][nt][1] + bi) << 16);
                u32 p1 = (u32)f2bf(acc[mt][nt][2] + bi) |
                         ((u32)f2bf(acc[mt][nt][3] + bi) << 16);
                *(uint2*)(out2 + (size_t)(b * 512 + hd) * 2048 + key) = make_uint2(p0, p1);
            } else {
#pragma unroll
                for (int r = 0; r < 4; r++) {
                    const int row = row0 + r;
                    float v = acc[mt][nt][r] + bi;
                    const size_t oi = (size_t)row * N + col;
                    if (EP == 1) {
                        float y = v * (0.79788456f + 0.035677408f * v * v);
                        y = fminf(y, 40.0f);
                        float tE = exp2f(y * 2.88539008f);
                        v = v * tE * __builtin_amdgcn_rcpf(tE + 1.0f);
                    }
                    if (qpart) v *= 0.18033688f;    // 0.125*log2(e) for attn exp2
                    if (EP == 2) outF[oi] = v + res[oi];
                    else         outB[oi] = f2bf(v);
                }
            }
        }
}

// ---------------------------------------------------------------------------
// Flash attention, transposed + max-free, key-split 2x, q-tile 128.
// Double-buffered K/V (2x16KB) + 2KB/wave P bounce = 40KB LDS, 4 blk/CU.
// Per kt: __syncthreads (drains PREVIOUS prefetch via its vmcnt(0)) ->
// issue kt+1 staging -> QK^T -> exp2+pack S->pp regs (s DIES: keeps peak
// regs ~116 < 128, no spill) -> sched_barrier -> V frags once (8 b128) ->
// per-nt {P write, pf read, PV}. LDS reads/wave/kt: 8K+8V+4P = 20 b128.
// XCD-aware decode: xcd = bid&7 = head h; per-XCD working set ~3MB < L2.
// ---------------------------------------------------------------------------
__global__ __launch_bounds__(256, 4) void k_attn(const u16* __restrict__ qkv,
                                                 const u16* __restrict__ vt,
                                                 u16* __restrict__ po0,
                                                 u16* __restrict__ po1,
                                                 float* __restrict__ pden) {
    __shared__ u16 smem[20480];              // 40 KB
    // bytes: [0,8K) Ks0 | [8K,16K) Vs0 | [16K,24K) Ks1 | [24K,32K) Vs1
    //        [32K,40K) P (2KB per wave, wave-private)
    const int bid = blockIdx.x;
    const int h = bid & 7, sg = bid >> 3;
    const int qt = sg & 15, kh = (sg >> 4) & 1, b = sg >> 5;
    const int q0 = qt << 7;
    const int t = threadIdx.x, lane = t & 63, w = t >> 6;
    const int quad = lane >> 4, l15 = lane & 15;
    const int x7 = l15 & 7;

    char* sb = (char*)smem;
    const char* gk = (const char*)qkv + (size_t)((b << 11) + (kh << 10)) * 3072 + 1024 + h * 128;
    const char* gv = (const char*)vt + (size_t)((b << 3) + h) * 64 * 4096 + (kh << 10) * 2;

    // ---- prologue: prefetch K/V tile 0 into buf0 (drained at first sync) ----
#pragma unroll
    for (int i = 0; i < 2; i++) {
        const int o4 = i * 4096 + t * 16;
        const int row = o4 >> 7;
        const int lc = ((o4 >> 4) & 7) ^ (row & 7);
        gload16(gk + (size_t)row * 3072 + lc * 16, sb + o4);
        gload16(gv + (size_t)row * 4096 + lc * 16, sb + 8192 + o4);
    }

    // ---- Q fragments straight from global (loop-invariant, 16B segments) ----
    bf16x8 qf[2][2];
    {
        const u16* gqp = qkv + (size_t)((b << 11) + q0 + w * 32 + l15) * 1536 + h * 64;
#pragma unroll
        for (int ks = 0; ks < 2; ks++)
#pragma unroll
            for (int nt = 0; nt < 2; nt++)
                qf[ks][nt] = *(const bf16x8*)(gqp + (size_t)(nt * 16) * 1536 + (ks * 4 + quad) * 8);
    }

    f32x4 accO[4][2];
    float denp[2] = {0.f, 0.f};
#pragma unroll
    for (int mt = 0; mt < 4; mt++)
#pragma unroll
        for (int nt = 0; nt < 2; nt++) accO[mt][nt] = (f32x4){0.f, 0.f, 0.f, 0.f};

    u16* Pw = smem + 16384 + w * 1024;       // 16 q-rows x 64 keys, this wave only

    for (int kt = 0; kt < 16; kt++) {
        const int cur = kt & 1;
        // drains own outstanding staging loads (vmcnt(0)) + barrier:
        // tile kt (issued one iteration ago) is now visible to all waves.
        __syncthreads();
        if (kt < 15) {                       // prefetch tile kt+1 into other buf
            const int kk2 = (kt + 1) << 6;
            char* db = sb + (cur ^ 1) * 16384;
#pragma unroll
            for (int i = 0; i < 2; i++) {
                const int o4 = i * 4096 + t * 16;
                const int row = o4 >> 7;
                const int lc = ((o4 >> 4) & 7) ^ (row & 7);
                gload16(gk + (size_t)(kk2 + row) * 3072 + lc * 16, db + o4);
                gload16(gv + (size_t)row * 4096 + (size_t)kk2 * 2 + lc * 16, db + 8192 + o4);
            }
        }
        const u16* Ksc = smem + cur * 8192;
        const u16* Vsc = Ksc + 4096;

        // S^T = K Q^T
        f32x4 s[4][2];
#pragma unroll
        for (int mt = 0; mt < 4; mt++)
#pragma unroll
            for (int nt = 0; nt < 2; nt++) s[mt][nt] = (f32x4){0.f, 0.f, 0.f, 0.f};
#pragma unroll
        for (int ks = 0; ks < 2; ks++) {
            const int cidx = ((ks * 4 + quad) ^ x7) * 8;
            bf16x8 kf[4];
#pragma unroll
            for (int mt = 0; mt < 4; mt++)
                kf[mt] = *(const bf16x8*)(Ksc + (mt * 16 + l15) * 64 + cidx);
            __builtin_amdgcn_s_setprio(1);
#pragma unroll
            for (int mt = 0; mt < 4; mt++)
#pragma unroll
                for (int nt = 0; nt < 2; nt++)
                    s[mt][nt] = __builtin_amdgcn_mfma_f32_16x16x32_bf16(
                        kf[mt], qf[ks][nt], s[mt][nt], 0, 0, 0);
            __builtin_amdgcn_s_setprio(0);
        }

        // exp2 + pack ALL groups NOW: s dies here, freeing 32 regs before
        // the V fragments are loaded (R9 held both -> spill).
        u32 pp[2][4][2];
#pragma unroll
        for (int nt = 0; nt < 2; nt++)
#pragma unroll
            for (int mt = 0; mt < 4; mt++) {
                const float p0 = __builtin_amdgcn_exp2f(s[mt][nt][0]);
                const float p1 = __builtin_amdgcn_exp2f(s[mt][nt][1]);
                const float p2 = __builtin_amdgcn_exp2f(s[mt][nt][2]);
                const float p3 = __builtin_amdgcn_exp2f(s[mt][nt][3]);
                denp[nt] += (p0 + p1) + (p2 + p3);
                pp[nt][mt][0] = pack_trunc(p0, p1);
                pp[nt][mt][1] = pack_trunc(p2, p3);
            }
        __builtin_amdgcn_sched_barrier(0);   // keep V loads BELOW the pack

        // V fragments: read ONCE per kt (reused by both nt) — 8 b128
        bf16x8 vf[2][4];
#pragma unroll
        for (int ks = 0; ks < 2; ks++) {
            const int cidx = ((ks * 4 + quad) ^ x7) * 8;
#pragma unroll
            for (int mt = 0; mt < 4; mt++)
                vf[ks][mt] = *(const bf16x8*)(Vsc + (mt * 16 + l15) * 64 + cidx);
        }

        // per 16-q group: P write (wave-private) -> pf read -> O^T += V^T P^T
#pragma unroll
        for (int nt = 0; nt < 2; nt++) {
#pragma unroll
            for (int mt = 0; mt < 4; mt++) {
                const int pidx = l15 * 64 +
                                 (((2 * mt + (quad >> 1)) ^ x7) << 3) + (quad & 1) * 4;
                *(uint2*)(&Pw[pidx]) = make_uint2(pp[nt][mt][0], pp[nt][mt][1]);
            }
#pragma unroll
            for (int ks = 0; ks < 2; ks++) {
                const int cidx = ((ks * 4 + quad) ^ x7) * 8;
                const bf16x8 pf = *(const bf16x8*)(Pw + l15 * 64 + cidx);
                __builtin_amdgcn_s_setprio(1);
#pragma unroll
                for (int mt = 0; mt < 4; mt++)
                    accO[mt][nt] = __builtin_amdgcn_mfma_f32_16x16x32_bf16(
                        vf[ks][mt], pf, accO[mt][nt], 0, 0, 0);
                __builtin_amdgcn_s_setprio(0);
            }
        }
    }

    // epilogue: partial den (quad-reduced) + raw partial O (bf16)
    u16* po = kh ? po1 : po0;
#pragma unroll
    for (int nt = 0; nt < 2; nt++) {
        float dn = denp[nt];
        dn += __shfl_xor(dn, 16, 64);
        dn += __shfl_xor(dn, 32, 64);
        if (quad == 0)
            pden[(size_t)(((kh << 5) + (b << 3) + h) << 11) + q0 + w * 32 + nt * 16 + l15] = dn;
#pragma unroll
        for (int mt = 0; mt < 4; mt++) {
            const int qg = q0 + w * 32 + nt * 16 + l15;
            const u32 p0 = (u32)f2bf(accO[mt][nt][0]) | ((u32)f2bf(accO[mt][nt][1]) << 16);
            const u32 p1 = (u32)f2bf(accO[mt][nt][2]) | ((u32)f2bf(accO[mt][nt][3]) << 16);
            *(uint2*)(po + (size_t)((b << 11) + qg) * 512 + h * 64 + mt * 16 + quad * 4) =
                make_uint2(p0, p1);
        }
    }
}

// ---------------------------------------------------------------------------
// Combine: o = (po0 + po1) / (den0 + den1), in-place over po0.
// ---------------------------------------------------------------------------
__global__ __launch_bounds__(256) void k_combine(u16* __restrict__ po0,
                                                 const u16* __restrict__ po1,
                                                 const float* __restrict__ pden) {
    const int idx8 = (blockIdx.x * 256 + threadIdx.x) * 8;
    const int row = idx8 >> 9, col = idx8 & 511;
    const int h = col >> 6, q = row & 2047, b = row >> 11;
    const size_t di = (size_t)(((b << 3) + h) << 11) + q;
    const float den = pden[di] + pden[di + (32 << 11)];
    const float r = __builtin_amdgcn_rcpf(den);
    uint4 a = *(const uint4*)(po0 + idx8);
    uint4 c = *(const uint4*)(po1 + idx8);
    u32 av[4] = {a.x, a.y, a.z, a.w}, cv[4] = {c.x, c.y, c.z, c.w}, ov[4];
#pragma unroll
    for (int i = 0; i < 4; i++) {
        const float lo = (f_from_bits(av[i] << 16) + f_from_bits(cv[i] << 16)) * r;
        const float hi = (f_from_bits(av[i] & 0xFFFF0000u) +
                          f_from_bits(cv[i] & 0xFFFF0000u)) * r;
        ov[i] = (u32)f2bf(lo) | ((u32)f2bf(hi) << 16);
    }
    *(uint4*)(po0 + idx8) = make_uint4(ov[0], ov[1], ov[2], ov[3]);
}

// ---------------------------------------------------------------------------
// Host-side pipeline.
// ---------------------------------------------------------------------------
extern "C" void kernel_launch(void* const* d_in, const int* in_sizes, int n_in,
                              void* d_out, int out_size, void* d_ws, size_t ws_size,
                              hipStream_t stream) {
    const float* x      = (const float*)d_in[0];
    const float* ln1_g  = (const float*)d_in[1];
    const float* ln1_b  = (const float*)d_in[2];
    const float* qkv_w  = (const float*)d_in[3];
    const float* qkv_b  = (const float*)d_in[4];
    const float* proj_w = (const float*)d_in[5];
    const float* proj_b = (const float*)d_in[6];
    const float* ln2_g  = (const float*)d_in[7];
    const float* ln2_b  = (const float*)d_in[8];
    const float* fc1_w  = (const float*)d_in[9];
    const float* fc1_b  = (const float*)d_in[10];
    const float* fc2_w  = (const float*)d_in[11];
    const float* fc2_b  = (const float*)d_in[12];
    float* out = (float*)d_out;
    char* ws = (char*)d_ws;

    u16*   qkv_wT = (u16*)(ws + 0);          // 1536x512  bf16
    u16*   proj_wT= (u16*)(ws + 1572864);    // 512x512
    u16*   fc1_wT = (u16*)(ws + 2097152);    // 2048x512
    u16*   fc2_wT = (u16*)(ws + 4194304);    // 512x2048
    u16*   h      = (u16*)(ws + 6291456);    // 8192x512 bf16 (LN outs)
    float* pden   = (float*)(ws + 6291456);  // 512KB, aliases h (dead in attn window)
    u16*   qkv    = (u16*)(ws + 14680064);   // 8192x1536
    u16*   vt     = (u16*)(ws + 39845888);   // [b*8+h][64 d][2048 key]
    u16*   o      = (u16*)(ws + 48234496);   // 8192x512 (= po0, combined in-place)
    u16*   po1    = (u16*)(ws + 56623104);   // aliases x1 (dead until proj)
    float* x1     = (float*)(ws + 56623104); // 8192x512 fp32
    u16*   f1     = (u16*)(ws + 14680064);   // 8192x2048 (reuse qkv+vt)
    u16*   h2     = h;

    // weights cast+T  +  LN1, one launch
    k_pre<<<5120, 256, 0, stream>>>(qkv_w, qkv_wT, proj_w, proj_wT,
                                    fc1_w, fc1_wT, fc2_w, fc2_wT,
                                    x, ln1_g, ln1_b, h);
    // QKV GEMM; Q cols pre-scaled, V cols -> vt transposed
    k_gemm<3,128><<<(8192/128)*(1536/128), 256, 0, stream>>>(
        h, qkv_wT, qkv_b, nullptr, nullptr, qkv, vt, 8192, 1536, 512);
    // attention, key-split 2x -> partials
    k_attn<<<1024, 256, 0, stream>>>(qkv, vt, o, po1, pden);
    k_combine<<<2048, 256, 0, stream>>>(o, po1, pden);
    // proj GEMM + residual(x) -> x1 fp32
    k_gemm<2,64><<<(8192/128)*(512/64), 256, 0, stream>>>(
        o, proj_wT, proj_b, x, x1, nullptr, nullptr, 8192, 512, 512);
    k_ln<<<2048, 256, 0, stream>>>(x1, ln2_g, ln2_b, h2);
    // FC1 + GELU
    k_gemm<1,128><<<(8192/128)*(2048/128), 256, 0, stream>>>(
        h2, fc1_wT, fc1_b, nullptr, nullptr, f1, nullptr, 8192, 2048, 512);
    // FC2 + residual(x1) -> out fp32
    k_gemm<2,64><<<(8192/128)*(512/64), 256, 0, stream>>>(
        f1, fc2_wT, fc2_b, x1, out, nullptr, nullptr, 8192, 512, 2048);
}

// Round 4
// 243.950 us; speedup vs baseline: 1.1526x; 1.0013x over previous
//
#include <hip/hip_runtime.h>
#include <math.h>

// ---------------------------------------------------------------------------
// TransformerBlock on MI355X (gfx950).  B=4, N=2048, C=512, H=8, D=64.
// All matmuls bf16 MFMA, fp32 accumulate. Residuals fp32.
// R11: k_attn -> 32x32x16 MFMA (T12 structure). P stays IN-REGISTER:
//      S^T C-layout (col=q=lane&31, row=key=(reg&3)+8(reg>>2)+4hi) reaches
//      the PV B-fragment (col=q, k=hi*8+j) with ONE permlane32_swap per
//      reg pair -> the P LDS bounce (12 DS ops/wave/kt) is deleted.
//      DS/wave/kt 336->240 cyc (binding pipe, -29%); LDS 40->32KB.
// ---------------------------------------------------------------------------

using bf16x8 = __attribute__((ext_vector_type(8))) short;
using f32x4  = __attribute__((ext_vector_type(4))) float;
using f32x16 = __attribute__((ext_vector_type(16))) float;

typedef unsigned short u16;
typedef unsigned int   u32;

__device__ __forceinline__ u16 f2bf(float f) {
    u32 u; __builtin_memcpy(&u, &f, 4);
    u32 r = u + 0x7FFFu + ((u >> 16) & 1u);   // RNE
    return (u16)(r >> 16);
}
__device__ __forceinline__ u32 fbits(float f) {
    u32 u; __builtin_memcpy(&u, &f, 4); return u;
}
__device__ __forceinline__ float f_from_bits(u32 u) {
    float f; __builtin_memcpy(&f, &u, 4); return f;
}
// pack two f32 -> two bf16 (truncation) in ONE v_perm_b32
__device__ __forceinline__ u32 pack_trunc(float lo, float hi) {
    return __builtin_amdgcn_perm(fbits(hi), fbits(lo), 0x07060302u);
}
// async global->LDS, 16B per lane; LDS dest = wave-uniform base + lane*16
__device__ __forceinline__ void gload16(const void* g, void* l) {
    __builtin_amdgcn_global_load_lds(
        (const __attribute__((address_space(1))) unsigned int*)g,
        (__attribute__((address_space(3))) unsigned int*)l, 16, 0, 0);
}

// ---------------------------------------------------------------------------
// Fused preprocessing: blocks 0..3071 = weight cast+transpose (4 weights),
// blocks 3072..5119 = LayerNorm1 (fp32 x -> bf16 h).
// ---------------------------------------------------------------------------
__global__ __launch_bounds__(256) void k_pre(
        const float* __restrict__ w0, u16* __restrict__ d0,   // 512x1536
        const float* __restrict__ w1, u16* __restrict__ d1,   // 512x512
        const float* __restrict__ w2, u16* __restrict__ d2,   // 512x2048
        const float* __restrict__ w3, u16* __restrict__ d3,   // 2048x512
        const float* __restrict__ x, const float* __restrict__ g,
        const float* __restrict__ bta, u16* __restrict__ hout) {
    __shared__ float tile[32][33];
    const int bid = blockIdx.x;
    if (bid < 3072) {
        const float* w; u16* dst; int K, N, tb;
        if (bid < 768)       { w = w0; dst = d0; K = 512;  N = 1536; tb = bid; }
        else if (bid < 1024) { w = w1; dst = d1; K = 512;  N = 512;  tb = bid - 768; }
        else if (bid < 2048) { w = w2; dst = d2; K = 512;  N = 2048; tb = bid - 1024; }
        else                 { w = w3; dst = d3; K = 2048; N = 512;  tb = bid - 2048; }
        const int nb = N >> 5;
        const int k0 = (tb / nb) << 5;
        const int n0 = (tb % nb) << 5;
        const int c = threadIdx.x & 31, r = threadIdx.x >> 5;
#pragma unroll
        for (int i = 0; i < 4; i++)
            tile[r + i * 8][c] = w[(size_t)(k0 + r + i * 8) * N + n0 + c];
        __syncthreads();
#pragma unroll
        for (int i = 0; i < 4; i++)
            dst[(size_t)(n0 + r + i * 8) * K + k0 + c] = f2bf(tile[c][r + i * 8]);
    } else {
        const int row  = ((bid - 3072) << 2) + (threadIdx.x >> 6);
        const int lane = threadIdx.x & 63;
        const float* xr = x + (size_t)row * 512 + lane * 8;
        float4 a = *(const float4*)xr;
        float4 c = *(const float4*)(xr + 4);
        float s = a.x + a.y + a.z + a.w + c.x + c.y + c.z + c.w;
        float q = a.x*a.x + a.y*a.y + a.z*a.z + a.w*a.w
                + c.x*c.x + c.y*c.y + c.z*c.z + c.w*c.w;
#pragma unroll
        for (int off = 32; off; off >>= 1) {
            s += __shfl_xor(s, off, 64);
            q += __shfl_xor(q, off, 64);
        }
        const float mean = s * (1.0f / 512.0f);
        const float var  = q * (1.0f / 512.0f) - mean * mean;
        const float rstd = rsqrtf(var + 1e-5f);
        float vv[8] = {a.x, a.y, a.z, a.w, c.x, c.y, c.z, c.w};
#pragma unroll
        for (int j = 0; j < 8; j++) {
            const int col = lane * 8 + j;
            hout[(size_t)row * 512 + col] = f2bf((vv[j] - mean) * rstd * g[col] + bta[col]);
        }
    }
}

// ---------------------------------------------------------------------------
// LayerNorm fp32 -> bf16 (standalone, for LN2).
// ---------------------------------------------------------------------------
__global__ __launch_bounds__(256) void k_ln(const float* __restrict__ x,
                                            const float* __restrict__ g,
                                            const float* __restrict__ bta,
                                            u16* __restrict__ out) {
    const int row  = (blockIdx.x << 2) + (threadIdx.x >> 6);
    const int lane = threadIdx.x & 63;
    const float* xr = x + (size_t)row * 512 + lane * 8;
    float4 a = *(const float4*)xr;
    float4 c = *(const float4*)(xr + 4);
    float s = a.x + a.y + a.z + a.w + c.x + c.y + c.z + c.w;
    float q = a.x*a.x + a.y*a.y + a.z*a.z + a.w*a.w
            + c.x*c.x + c.y*c.y + c.z*c.z + c.w*c.w;
#pragma unroll
    for (int off = 32; off; off >>= 1) {
        s += __shfl_xor(s, off, 64);
        q += __shfl_xor(q, off, 64);
    }
    const float mean = s * (1.0f / 512.0f);
    const float var  = q * (1.0f / 512.0f) - mean * mean;
    const float rstd = rsqrtf(var + 1e-5f);
    float vv[8] = {a.x, a.y, a.z, a.w, c.x, c.y, c.z, c.w};
#pragma unroll
    for (int j = 0; j < 8; j++) {
        const int col = lane * 8 + j;
        out[(size_t)row * 512 + col] = f2bf((vv[j] - mean) * rstd * g[col] + bta[col]);
    }
}

// ---------------------------------------------------------------------------
// GEMM: C[M,N] = A[M,K](bf16) @ Bt[N,K]^T + bias. m97 staging, BK=64,
// 128xTN tile. XCD-grouped decode: xcd = bid&7 owns m-rows m%8==xcd ->
// A-tiles fetched by exactly one XCD; B (<=2MB) L2-resident per XCD.
// EP=1: +tanh-GELU -> bf16.  EP=2: +fp32 residual -> fp32.
// EP=3: QKV — Q cols (<512) pre-scaled by 0.125*log2e, V cols -> vt transposed.
// 8-chunk XOR swizzle (chunk ^= row&7): b128 reads 2-way (free).
// ---------------------------------------------------------------------------
template <int EP, int TN>
__global__ __launch_bounds__(256, 3) void k_gemm(const u16* __restrict__ A,
                                                 const u16* __restrict__ Bt,
                                                 const float* __restrict__ bias,
                                                 const float* __restrict__ res,
                                                 float* __restrict__ outF,
                                                 u16* __restrict__ outB,
                                                 u16* __restrict__ out2,
                                                 int M, int N, int K) {
    constexpr int NT = TN / 32;
    __shared__ u16 As[128 * 64];
    __shared__ u16 Bs[TN * 64];
    const int nb = N / TN;
    // XCD-grouped block decode (grid = (M/128)*nb, M/128 divisible by 8):
    // x = bid&7 -> XCD; within XCD: n fastest (B cycles, L2-resident),
    // m-group slowest (A-tile hot across nb consecutive slots).
    const int xg = blockIdx.x & 7, sg = blockIdx.x >> 3;
    const int m0 = ((sg / nb) * 8 + xg) << 7;
    const int n0 = (sg % nb) * TN;
    const int t = threadIdx.x, lane = t & 63, w = t >> 6;
    const int wr = (w >> 1) << 6;
    const int wc = (w & 1) * (TN / 2);
    const int quad = lane >> 4, l15 = lane & 15;
    const int x7 = l15 & 7;

    f32x4 acc[4][NT];
#pragma unroll
    for (int i = 0; i < 4; i++)
#pragma unroll
        for (int j = 0; j < NT; j++) acc[i][j] = (f32x4){0.f, 0.f, 0.f, 0.f};

    const size_t Kb = (size_t)K * 2;
    const char* ga = (const char*)A + (size_t)m0 * Kb;
    const char* gb = (const char*)Bt + (size_t)n0 * Kb;
    const int o0 = t * 16;

    for (int k0 = 0; k0 < K; k0 += 64) {
        const int kb = k0 * 2;
#pragma unroll
        for (int i = 0; i < 4; i++) {              // A: 128 rows x 128B
            const int o4 = i * 4096 + o0;
            const int row = o4 >> 7;
            const int lc = ((o4 >> 4) & 7) ^ (row & 7);
            gload16(ga + (size_t)row * Kb + kb + lc * 16, (char*)As + o4);
        }
#pragma unroll
        for (int i = 0; i < TN / 32; i++) {        // B: TN rows x 128B
            const int o4 = i * 4096 + o0;
            const int row = o4 >> 7;
            const int lc = ((o4 >> 4) & 7) ^ (row & 7);
            gload16(gb + (size_t)row * Kb + kb + lc * 16, (char*)Bs + o4);
        }
        __syncthreads();
#pragma unroll
        for (int ks = 0; ks < 2; ks++) {
            const int cidx = ((ks * 4 + quad) ^ x7) * 8;
            bf16x8 af[4], bfr[NT];
#pragma unroll
            for (int i = 0; i < 4; i++)
                af[i] = *(const bf16x8*)(As + (wr + i * 16 + l15) * 64 + cidx);
#pragma unroll
            for (int j = 0; j < NT; j++)
                bfr[j] = *(const bf16x8*)(Bs + (wc + j * 16 + l15) * 64 + cidx);
#pragma unroll
            for (int mt = 0; mt < 4; mt++)
#pragma unroll
                for (int nt = 0; nt < NT; nt++)
                    acc[mt][nt] = __builtin_amdgcn_mfma_f32_16x16x32_bf16(
                        af[mt], bfr[nt], acc[mt][nt], 0, 0, 0);
        }
        __syncthreads();
    }

    const bool vpart = (EP == 3) && (n0 >= 1024);          // block-uniform
    const bool qpart = (EP == 3) && (n0 < 512);            // block-uniform
#pragma unroll
    for (int mt = 0; mt < 4; mt++)
#pragma unroll
        for (int nt = 0; nt < NT; nt++) {
            const int col = n0 + wc + nt * 16 + l15;
            const float bi = bias[col];
            const int row0 = m0 + wr + mt * 16 + quad * 4;
            if (vpart) {
                const int b = row0 >> 11, key = row0 & 2047;
                const int hd = col - 1024;          // h*64 + d
                u32 p0 = (u32)f2bf(acc[mt][nt][0] + bi) |
                         ((u32)f2bf(acc[mt][nt][1] + bi) << 16);
                u32 p1 = (u32)f2bf(acc[mt][nt][2] + bi) |
                         ((u32)f2bf(acc[mt][nt][3] + bi) << 16);
                *(uint2*)(out2 + (size_t)(b * 512 + hd) * 2048 + key) = make_uint2(p0, p1);
            } else {
#pragma unroll
                for (int r = 0; r < 4; r++) {
                    const int row = row0 + r;
                    float v = acc[mt][nt][r] + bi;
                    const size_t oi = (size_t)row * N + col;
                    if (EP == 1) {
                        float y = v * (0.79788456f + 0.035677408f * v * v);
                        y = fminf(y, 40.0f);
                        float tE = exp2f(y * 2.88539008f);
                        v = v * tE * __builtin_amdgcn_rcpf(tE + 1.0f);
                    }
                    if (qpart) v *= 0.18033688f;    // 0.125*log2(e) for attn exp2
                    if (EP == 2) outF[oi] = v + res[oi];
                    else         outB[oi] = f2bf(v);
                }
            }
        }
}

// ---------------------------------------------------------------------------
// Flash attention, 32x32x16 MFMA, transposed + max-free, key-split 2x,
// q-tile 128 (32 q/wave).  Double-buffered K/V = 32KB LDS, no P buffer.
// Per kt: __syncthreads (drains PREVIOUS prefetch via its vmcnt(0)) ->
// issue kt+1 staging -> QK^T (8 MFMA) -> exp2 + pack + permlane32_swap
// (P fully in-register; S^T C-layout row=key=(reg&3)+8(reg>>2)+4hi maps to
// PV B-frag k=hi*8+j with one swap per reg pair) -> PV (8 MFMA).
// DS/wave/kt: 8 K-frag + 8 V-frag b128 reads only.
// XCD-aware decode: xcd = bid&7 = head h; per-XCD working set ~3MB < L2.
// ---------------------------------------------------------------------------
__global__ __launch_bounds__(256, 4) void k_attn(const u16* __restrict__ qkv,
                                                 const u16* __restrict__ vt,
                                                 u16* __restrict__ po0,
                                                 u16* __restrict__ po1,
                                                 float* __restrict__ pden) {
    __shared__ u16 smem[16384];              // 32 KB
    // bytes: [0,8K) Ks0 | [8K,16K) Vs0 | [16K,24K) Ks1 | [24K,32K) Vs1
    const int bid = blockIdx.x;
    const int h = bid & 7, sg = bid >> 3;
    const int qt = sg & 15, kh = (sg >> 4) & 1, b = sg >> 5;
    const int q0 = qt << 7;
    const int t = threadIdx.x, lane = t & 63, w = t >> 6;
    const int l31 = lane & 31, hi = lane >> 5;
    const int x7 = l31 & 7;

    char* sb = (char*)smem;
    const char* gk = (const char*)qkv + (size_t)((b << 11) + (kh << 10)) * 3072 + 1024 + h * 128;
    const char* gv = (const char*)vt + (size_t)((b << 3) + h) * 64 * 4096 + (kh << 10) * 2;

    // ---- prologue: prefetch K/V tile 0 into buf0 (drained at first sync) ----
#pragma unroll
    for (int i = 0; i < 2; i++) {
        const int o4 = i * 4096 + t * 16;
        const int row = o4 >> 7;
        const int lc = ((o4 >> 4) & 7) ^ (row & 7);
        gload16(gk + (size_t)row * 3072 + lc * 16, sb + o4);
        gload16(gv + (size_t)row * 4096 + lc * 16, sb + 8192 + o4);
    }

    // ---- Q fragments straight from global (loop-invariant B-frags) ----
    // B-frag 32x32x16: col=q=lane&31, k = ks*16 + hi*8 + j
    bf16x8 qf[4];
    {
        const u16* gqp = qkv + (size_t)((b << 11) + q0 + w * 32 + l31) * 1536 + h * 64 + hi * 8;
#pragma unroll
        for (int ks = 0; ks < 4; ks++)
            qf[ks] = *(const bf16x8*)(gqp + ks * 16);
    }

    f32x16 accO[2];
#pragma unroll
    for (int i = 0; i < 16; i++) { accO[0][i] = 0.f; accO[1][i] = 0.f; }
    float dn = 0.f;

    for (int kt = 0; kt < 16; kt++) {
        const int cur = kt & 1;
        // drains own outstanding staging loads (vmcnt(0)) + barrier:
        // tile kt (issued one iteration ago) is now visible to all waves.
        __syncthreads();
        if (kt < 15) {                       // prefetch tile kt+1 into other buf
            const int kk2 = (kt + 1) << 6;
            char* db = sb + (cur ^ 1) * 16384;
#pragma unroll
            for (int i = 0; i < 2; i++) {
                const int o4 = i * 4096 + t * 16;
                const int row = o4 >> 7;
                const int lc = ((o4 >> 4) & 7) ^ (row & 7);
                gload16(gk + (size_t)(kk2 + row) * 3072 + lc * 16, db + o4);
                gload16(gv + (size_t)row * 4096 + (size_t)kk2 * 2 + lc * 16, db + 8192 + o4);
            }
        }
        const u16* Ksc = smem + cur * 8192;
        const u16* Vsc = Ksc + 4096;

        // S^T = K Q^T  (A = K frag: row=key=lane&31 (+32mt), k=ks*16+hi*8+j)
        f32x16 s2[2];
#pragma unroll
        for (int i = 0; i < 16; i++) { s2[0][i] = 0.f; s2[1][i] = 0.f; }
#pragma unroll
        for (int ks = 0; ks < 4; ks++) {
            const int cx = ((ks * 2 + hi) ^ x7) * 8;
            bf16x8 kf0 = *(const bf16x8*)(Ksc + l31 * 64 + cx);
            bf16x8 kf1 = *(const bf16x8*)(Ksc + (32 + l31) * 64 + cx);
            __builtin_amdgcn_s_setprio(1);
            s2[0] = __builtin_amdgcn_mfma_f32_32x32x16_bf16(kf0, qf[ks], s2[0], 0, 0, 0);
            s2[1] = __builtin_amdgcn_mfma_f32_32x32x16_bf16(kf1, qf[ks], s2[1], 0, 0, 0);
            __builtin_amdgcn_s_setprio(0);
        }

        // p = exp2(s); pack to bf16 pairs; permlane32_swap -> PV B-frags.
        // Source reg r of s2[mt]: key = mt*32 + (r&3) + 8*(r>>2) + 4*hi.
        // pk[c][m] = keys (8c + 4hi + 2m, +1).  For pf[ks=mt*2+ksl]:
        // swap(pk[2ksl][m], pk[2ksl+1][m]) -> res[0]=reg m, res[1]=reg m+2.
        u32 pfu[4][4];
#pragma unroll
        for (int mt = 0; mt < 2; mt++) {
            float pv[16];
#pragma unroll
            for (int r = 0; r < 16; r++) {
                pv[r] = __builtin_amdgcn_exp2f(s2[mt][r]);
                dn += pv[r];
            }
            u32 pk[4][2];
#pragma unroll
            for (int c = 0; c < 4; c++)
#pragma unroll
                for (int m = 0; m < 2; m++)
                    pk[c][m] = pack_trunc(pv[4 * c + 2 * m], pv[4 * c + 2 * m + 1]);
#pragma unroll
            for (int ksl = 0; ksl < 2; ksl++)
#pragma unroll
                for (int m = 0; m < 2; m++) {
                    auto rr = __builtin_amdgcn_permlane32_swap(
                        pk[ksl * 2][m], pk[ksl * 2 + 1][m], false, false);
                    pfu[mt * 2 + ksl][m]     = rr[0];
                    pfu[mt * 2 + ksl][m + 2] = rr[1];
                }
        }
        __builtin_amdgcn_sched_barrier(0);   // keep V reads below the pack

        // O^T += V^T P^T  (A = V^T frag: row=d=lane&31 (+32mtd), k=key)
#pragma unroll
        for (int ks = 0; ks < 4; ks++) {
            u32 pw[4] = {pfu[ks][0], pfu[ks][1], pfu[ks][2], pfu[ks][3]};
            bf16x8 pfv;
            __builtin_memcpy(&pfv, pw, 16);
            const int cx = ((ks * 2 + hi) ^ x7) * 8;
            bf16x8 vf0 = *(const bf16x8*)(Vsc + l31 * 64 + cx);
            bf16x8 vf1 = *(const bf16x8*)(Vsc + (32 + l31) * 64 + cx);
            __builtin_amdgcn_s_setprio(1);
            accO[0] = __builtin_amdgcn_mfma_f32_32x32x16_bf16(vf0, pfv, accO[0], 0, 0, 0);
            accO[1] = __builtin_amdgcn_mfma_f32_32x32x16_bf16(vf1, pfv, accO[1], 0, 0, 0);
            __builtin_amdgcn_s_setprio(0);
        }
    }

    // epilogue: den (hi-half reduce) + raw partial O (bf16)
    u16* po = kh ? po1 : po0;
    dn += __shfl_xor(dn, 32, 64);
    const int qg = q0 + w * 32 + l31;
    if (hi == 0)
        pden[(size_t)(((kh << 5) + (b << 3) + h) << 11) + qg] = dn;
#pragma unroll
    for (int mtd = 0; mtd < 2; mtd++)
#pragma unroll
        for (int g = 0; g < 4; g++) {
            // acc reg 4g+t -> d = mtd*32 + 8g + 4hi + t
            const u32 p0 = (u32)f2bf(accO[mtd][4 * g + 0]) |
                           ((u32)f2bf(accO[mtd][4 * g + 1]) << 16);
            const u32 p1 = (u32)f2bf(accO[mtd][4 * g + 2]) |
                           ((u32)f2bf(accO[mtd][4 * g + 3]) << 16);
            const int d0 = mtd * 32 + g * 8 + hi * 4;
            *(uint2*)(po + (size_t)((b << 11) + qg) * 512 + h * 64 + d0) =
                make_uint2(p0, p1);
        }
}

// ---------------------------------------------------------------------------
// Combine: o = (po0 + po1) / (den0 + den1), in-place over po0.
// ---------------------------------------------------------------------------
__global__ __launch_bounds__(256) void k_combine(u16* __restrict__ po0,
                                                 const u16* __restrict__ po1,
                                                 const float* __restrict__ pden) {
    const int idx8 = (blockIdx.x * 256 + threadIdx.x) * 8;
    const int row = idx8 >> 9, col = idx8 & 511;
    const int h = col >> 6, q = row & 2047, b = row >> 11;
    const size_t di = (size_t)(((b << 3) + h) << 11) + q;
    const float den = pden[di] + pden[di + (32 << 11)];
    const float r = __builtin_amdgcn_rcpf(den);
    uint4 a = *(const uint4*)(po0 + idx8);
    uint4 c = *(const uint4*)(po1 + idx8);
    u32 av[4] = {a.x, a.y, a.z, a.w}, cv[4] = {c.x, c.y, c.z, c.w}, ov[4];
#pragma unroll
    for (int i = 0; i < 4; i++) {
        const float lo = (f_from_bits(av[i] << 16) + f_from_bits(cv[i] << 16)) * r;
        const float hi = (f_from_bits(av[i] & 0xFFFF0000u) +
                          f_from_bits(cv[i] & 0xFFFF0000u)) * r;
        ov[i] = (u32)f2bf(lo) | ((u32)f2bf(hi) << 16);
    }
    *(uint4*)(po0 + idx8) = make_uint4(ov[0], ov[1], ov[2], ov[3]);
}

// ---------------------------------------------------------------------------
// Host-side pipeline.
// ---------------------------------------------------------------------------
extern "C" void kernel_launch(void* const* d_in, const int* in_sizes, int n_in,
                              void* d_out, int out_size, void* d_ws, size_t ws_size,
                              hipStream_t stream) {
    const float* x      = (const float*)d_in[0];
    const float* ln1_g  = (const float*)d_in[1];
    const float* ln1_b  = (const float*)d_in[2];
    const float* qkv_w  = (const float*)d_in[3];
    const float* qkv_b  = (const float*)d_in[4];
    const float* proj_w = (const float*)d_in[5];
    const float* proj_b = (const float*)d_in[6];
    const float* ln2_g  = (const float*)d_in[7];
    const float* ln2_b  = (const float*)d_in[8];
    const float* fc1_w  = (const float*)d_in[9];
    const float* fc1_b  = (const float*)d_in[10];
    const float* fc2_w  = (const float*)d_in[11];
    const float* fc2_b  = (const float*)d_in[12];
    float* out = (float*)d_out;
    char* ws = (char*)d_ws;

    u16*   qkv_wT = (u16*)(ws + 0);          // 1536x512  bf16
    u16*   proj_wT= (u16*)(ws + 1572864);    // 512x512
    u16*   fc1_wT = (u16*)(ws + 2097152);    // 2048x512
    u16*   fc2_wT = (u16*)(ws + 4194304);    // 512x2048
    u16*   h      = (u16*)(ws + 6291456);    // 8192x512 bf16 (LN outs)
    float* pden   = (float*)(ws + 6291456);  // 512KB, aliases h (dead in attn window)
    u16*   qkv    = (u16*)(ws + 14680064);   // 8192x1536
    u16*   vt     = (u16*)(ws + 39845888);   // [b*8+h][64 d][2048 key]
    u16*   o      = (u16*)(ws + 48234496);   // 8192x512 (= po0, combined in-place)
    u16*   po1    = (u16*)(ws + 56623104);   // aliases x1 (dead until proj)
    float* x1     = (float*)(ws + 56623104); // 8192x512 fp32
    u16*   f1     = (u16*)(ws + 14680064);   // 8192x2048 (reuse qkv+vt)
    u16*   h2     = h;

    // weights cast+T  +  LN1, one launch
    k_pre<<<5120, 256, 0, stream>>>(qkv_w, qkv_wT, proj_w, proj_wT,
                                    fc1_w, fc1_wT, fc2_w, fc2_wT,
                                    x, ln1_g, ln1_b, h);
    // QKV GEMM; Q cols pre-scaled, V cols -> vt transposed
    k_gemm<3,128><<<(8192/128)*(1536/128), 256, 0, stream>>>(
        h, qkv_wT, qkv_b, nullptr, nullptr, qkv, vt, 8192, 1536, 512);
    // attention, key-split 2x -> partials
    k_attn<<<1024, 256, 0, stream>>>(qkv, vt, o, po1, pden);
    k_combine<<<2048, 256, 0, stream>>>(o, po1, pden);
    // proj GEMM + residual(x) -> x1 fp32
    k_gemm<2,64><<<(8192/128)*(512/64), 256, 0, stream>>>(
        o, proj_wT, proj_b, x, x1, nullptr, nullptr, 8192, 512, 512);
    k_ln<<<2048, 256, 0, stream>>>(x1, ln2_g, ln2_b, h2);
    // FC1 + GELU
    k_gemm<1,128><<<(8192/128)*(2048/128), 256, 0, stream>>>(
        h2, fc1_wT, fc1_b, nullptr, nullptr, f1, nullptr, 8192, 2048, 512);
    // FC2 + residual(x1) -> out fp32
    k_gemm<2,64><<<(8192/128)*(512/64), 256, 0, stream>>>(
        f1, fc2_wT, fc2_b, x1, out, nullptr, nullptr, 8192, 512, 2048);
}

// Round 5
// 234.315 us; speedup vs baseline: 1.2000x; 1.0411x over previous
//
#include <hip/hip_runtime.h>
#include <math.h>

// ---------------------------------------------------------------------------
// TransformerBlock on MI355X (gfx950).  B=4, N=2048, C=512, H=8, D=64.
// All matmuls bf16 MFMA, fp32 accumulate. Residuals fp32.
// R12: merge k_attn's key-split (kh 2x -> 1): one block does all 32 K/V
//      tiles, divides by den in-register, writes FINAL o. k_combine kernel
//      deleted (8 -> 7 dispatches; -32MB HBM of partials/combine traffic).
//      Measured occupancy was ~28% with the split anyway, so the nominal
//      concurrency loss (1024->512 blocks) is expected ~free.
//      Also removed sched_barrier(0): at VGPR 56 there's headroom, let the
//      scheduler hoist V ds_reads above exp2/pack to hide their latency.
// ---------------------------------------------------------------------------

using bf16x8 = __attribute__((ext_vector_type(8))) short;
using f32x4  = __attribute__((ext_vector_type(4))) float;
using f32x16 = __attribute__((ext_vector_type(16))) float;

typedef unsigned short u16;
typedef unsigned int   u32;

__device__ __forceinline__ u16 f2bf(float f) {
    u32 u; __builtin_memcpy(&u, &f, 4);
    u32 r = u + 0x7FFFu + ((u >> 16) & 1u);   // RNE
    return (u16)(r >> 16);
}
__device__ __forceinline__ u32 fbits(float f) {
    u32 u; __builtin_memcpy(&u, &f, 4); return u;
}
__device__ __forceinline__ float f_from_bits(u32 u) {
    float f; __builtin_memcpy(&f, &u, 4); return f;
}
// pack two f32 -> two bf16 (truncation) in ONE v_perm_b32
__device__ __forceinline__ u32 pack_trunc(float lo, float hi) {
    return __builtin_amdgcn_perm(fbits(hi), fbits(lo), 0x07060302u);
}
// async global->LDS, 16B per lane; LDS dest = wave-uniform base + lane*16
__device__ __forceinline__ void gload16(const void* g, void* l) {
    __builtin_amdgcn_global_load_lds(
        (const __attribute__((address_space(1))) unsigned int*)g,
        (__attribute__((address_space(3))) unsigned int*)l, 16, 0, 0);
}

// ---------------------------------------------------------------------------
// Fused preprocessing: blocks 0..3071 = weight cast+transpose (4 weights),
// blocks 3072..5119 = LayerNorm1 (fp32 x -> bf16 h).
// ---------------------------------------------------------------------------
__global__ __launch_bounds__(256) void k_pre(
        const float* __restrict__ w0, u16* __restrict__ d0,   // 512x1536
        const float* __restrict__ w1, u16* __restrict__ d1,   // 512x512
        const float* __restrict__ w2, u16* __restrict__ d2,   // 512x2048
        const float* __restrict__ w3, u16* __restrict__ d3,   // 2048x512
        const float* __restrict__ x, const float* __restrict__ g,
        const float* __restrict__ bta, u16* __restrict__ hout) {
    __shared__ float tile[32][33];
    const int bid = blockIdx.x;
    if (bid < 3072) {
        const float* w; u16* dst; int K, N, tb;
        if (bid < 768)       { w = w0; dst = d0; K = 512;  N = 1536; tb = bid; }
        else if (bid < 1024) { w = w1; dst = d1; K = 512;  N = 512;  tb = bid - 768; }
        else if (bid < 2048) { w = w2; dst = d2; K = 512;  N = 2048; tb = bid - 1024; }
        else                 { w = w3; dst = d3; K = 2048; N = 512;  tb = bid - 2048; }
        const int nb = N >> 5;
        const int k0 = (tb / nb) << 5;
        const int n0 = (tb % nb) << 5;
        const int c = threadIdx.x & 31, r = threadIdx.x >> 5;
#pragma unroll
        for (int i = 0; i < 4; i++)
            tile[r + i * 8][c] = w[(size_t)(k0 + r + i * 8) * N + n0 + c];
        __syncthreads();
#pragma unroll
        for (int i = 0; i < 4; i++)
            dst[(size_t)(n0 + r + i * 8) * K + k0 + c] = f2bf(tile[c][r + i * 8]);
    } else {
        const int row  = ((bid - 3072) << 2) + (threadIdx.x >> 6);
        const int lane = threadIdx.x & 63;
        const float* xr = x + (size_t)row * 512 + lane * 8;
        float4 a = *(const float4*)xr;
        float4 c = *(const float4*)(xr + 4);
        float s = a.x + a.y + a.z + a.w + c.x + c.y + c.z + c.w;
        float q = a.x*a.x + a.y*a.y + a.z*a.z + a.w*a.w
                + c.x*c.x + c.y*c.y + c.z*c.z + c.w*c.w;
#pragma unroll
        for (int off = 32; off; off >>= 1) {
            s += __shfl_xor(s, off, 64);
            q += __shfl_xor(q, off, 64);
        }
        const float mean = s * (1.0f / 512.0f);
        const float var  = q * (1.0f / 512.0f) - mean * mean;
        const float rstd = rsqrtf(var + 1e-5f);
        float vv[8] = {a.x, a.y, a.z, a.w, c.x, c.y, c.z, c.w};
#pragma unroll
        for (int j = 0; j < 8; j++) {
            const int col = lane * 8 + j;
            hout[(size_t)row * 512 + col] = f2bf((vv[j] - mean) * rstd * g[col] + bta[col]);
        }
    }
}

// ---------------------------------------------------------------------------
// LayerNorm fp32 -> bf16 (standalone, for LN2).
// ---------------------------------------------------------------------------
__global__ __launch_bounds__(256) void k_ln(const float* __restrict__ x,
                                            const float* __restrict__ g,
                                            const float* __restrict__ bta,
                                            u16* __restrict__ out) {
    const int row  = (blockIdx.x << 2) + (threadIdx.x >> 6);
    const int lane = threadIdx.x & 63;
    const float* xr = x + (size_t)row * 512 + lane * 8;
    float4 a = *(const float4*)xr;
    float4 c = *(const float4*)(xr + 4);
    float s = a.x + a.y + a.z + a.w + c.x + c.y + c.z + c.w;
    float q = a.x*a.x + a.y*a.y + a.z*a.z + a.w*a.w
            + c.x*c.x + c.y*c.y + c.z*c.z + c.w*c.w;
#pragma unroll
    for (int off = 32; off; off >>= 1) {
        s += __shfl_xor(s, off, 64);
        q += __shfl_xor(q, off, 64);
    }
    const float mean = s * (1.0f / 512.0f);
    const float var  = q * (1.0f / 512.0f) - mean * mean;
    const float rstd = rsqrtf(var + 1e-5f);
    float vv[8] = {a.x, a.y, a.z, a.w, c.x, c.y, c.z, c.w};
#pragma unroll
    for (int j = 0; j < 8; j++) {
        const int col = lane * 8 + j;
        out[(size_t)row * 512 + col] = f2bf((vv[j] - mean) * rstd * g[col] + bta[col]);
    }
}

// ---------------------------------------------------------------------------
// GEMM: C[M,N] = A[M,K](bf16) @ Bt[N,K]^T + bias. m97 staging, BK=64,
// 128xTN tile. XCD-grouped decode: xcd = bid&7 owns m-rows m%8==xcd ->
// A-tiles fetched by exactly one XCD; B (<=2MB) L2-resident per XCD.
// EP=1: +tanh-GELU -> bf16.  EP=2: +fp32 residual -> fp32.
// EP=3: QKV — Q cols (<512) pre-scaled by 0.125*log2e, V cols -> vt transposed.
// 8-chunk XOR swizzle (chunk ^= row&7): b128 reads 2-way (free).
// ---------------------------------------------------------------------------
template <int EP, int TN>
__global__ __launch_bounds__(256, 3) void k_gemm(const u16* __restrict__ A,
                                                 const u16* __restrict__ Bt,
                                                 const float* __restrict__ bias,
                                                 const float* __restrict__ res,
                                                 float* __restrict__ outF,
                                                 u16* __restrict__ outB,
                                                 u16* __restrict__ out2,
                                                 int M, int N, int K) {
    constexpr int NT = TN / 32;
    __shared__ u16 As[128 * 64];
    __shared__ u16 Bs[TN * 64];
    const int nb = N / TN;
    // XCD-grouped block decode (grid = (M/128)*nb, M/128 divisible by 8):
    // x = bid&7 -> XCD; within XCD: n fastest (B cycles, L2-resident),
    // m-group slowest (A-tile hot across nb consecutive slots).
    const int xg = blockIdx.x & 7, sg = blockIdx.x >> 3;
    const int m0 = ((sg / nb) * 8 + xg) << 7;
    const int n0 = (sg % nb) * TN;
    const int t = threadIdx.x, lane = t & 63, w = t >> 6;
    const int wr = (w >> 1) << 6;
    const int wc = (w & 1) * (TN / 2);
    const int quad = lane >> 4, l15 = lane & 15;
    const int x7 = l15 & 7;

    f32x4 acc[4][NT];
#pragma unroll
    for (int i = 0; i < 4; i++)
#pragma unroll
        for (int j = 0; j < NT; j++) acc[i][j] = (f32x4){0.f, 0.f, 0.f, 0.f};

    const size_t Kb = (size_t)K * 2;
    const char* ga = (const char*)A + (size_t)m0 * Kb;
    const char* gb = (const char*)Bt + (size_t)n0 * Kb;
    const int o0 = t * 16;

    for (int k0 = 0; k0 < K; k0 += 64) {
        const int kb = k0 * 2;
#pragma unroll
        for (int i = 0; i < 4; i++) {              // A: 128 rows x 128B
            const int o4 = i * 4096 + o0;
            const int row = o4 >> 7;
            const int lc = ((o4 >> 4) & 7) ^ (row & 7);
            gload16(ga + (size_t)row * Kb + kb + lc * 16, (char*)As + o4);
        }
#pragma unroll
        for (int i = 0; i < TN / 32; i++) {        // B: TN rows x 128B
            const int o4 = i * 4096 + o0;
            const int row = o4 >> 7;
            const int lc = ((o4 >> 4) & 7) ^ (row & 7);
            gload16(gb + (size_t)row * Kb + kb + lc * 16, (char*)Bs + o4);
        }
        __syncthreads();
#pragma unroll
        for (int ks = 0; ks < 2; ks++) {
            const int cidx = ((ks * 4 + quad) ^ x7) * 8;
            bf16x8 af[4], bfr[NT];
#pragma unroll
            for (int i = 0; i < 4; i++)
                af[i] = *(const bf16x8*)(As + (wr + i * 16 + l15) * 64 + cidx);
#pragma unroll
            for (int j = 0; j < NT; j++)
                bfr[j] = *(const bf16x8*)(Bs + (wc + j * 16 + l15) * 64 + cidx);
#pragma unroll
            for (int mt = 0; mt < 4; mt++)
#pragma unroll
                for (int nt = 0; nt < NT; nt++)
                    acc[mt][nt] = __builtin_amdgcn_mfma_f32_16x16x32_bf16(
                        af[mt], bfr[nt], acc[mt][nt], 0, 0, 0);
        }
        __syncthreads();
    }

    const bool vpart = (EP == 3) && (n0 >= 1024);          // block-uniform
    const bool qpart = (EP == 3) && (n0 < 512);            // block-uniform
#pragma unroll
    for (int mt = 0; mt < 4; mt++)
#pragma unroll
        for (int nt = 0; nt < NT; nt++) {
            const int col = n0 + wc + nt * 16 + l15;
            const float bi = bias[col];
            const int row0 = m0 + wr + mt * 16 + quad * 4;
            if (vpart) {
                const int b = row0 >> 11, key = row0 & 2047;
                const int hd = col - 1024;          // h*64 + d
                u32 p0 = (u32)f2bf(acc[mt][nt][0] + bi) |
                         ((u32)f2bf(acc[mt][nt][1] + bi) << 16);
                u32 p1 = (u32)f2bf(acc[mt][nt][2] + bi) |
                         ((u32)f2bf(acc[mt][nt][3] + bi) << 16);
                *(uint2*)(out2 + (size_t)(b * 512 + hd) * 2048 + key) = make_uint2(p0, p1);
            } else {
#pragma unroll
                for (int r = 0; r < 4; r++) {
                    const int row = row0 + r;
                    float v = acc[mt][nt][r] + bi;
                    const size_t oi = (size_t)row * N + col;
                    if (EP == 1) {
                        float y = v * (0.79788456f + 0.035677408f * v * v);
                        y = fminf(y, 40.0f);
                        float tE = exp2f(y * 2.88539008f);
                        v = v * tE * __builtin_amdgcn_rcpf(tE + 1.0f);
                    }
                    if (qpart) v *= 0.18033688f;    // 0.125*log2(e) for attn exp2
                    if (EP == 2) outF[oi] = v + res[oi];
                    else         outB[oi] = f2bf(v);
                }
            }
        }
}

// ---------------------------------------------------------------------------
// Flash attention, 32x32x16 MFMA, transposed + max-free, NO key-split:
// each block walks all 32 K/V tiles (2048 keys) and writes FINAL o
// (divided by den in-register).  Double-buffered K/V = 32KB LDS.
// Per kt: __syncthreads (drains PREVIOUS prefetch via its vmcnt(0)) ->
// issue kt+1 staging -> QK^T (8 MFMA) -> exp2 + pack + permlane32_swap
// (P fully in-register; S^T C-layout row=key=(reg&3)+8(reg>>2)+4hi maps to
// PV B-frag k=hi*8+j with one swap per reg pair) -> PV (8 MFMA).
// DS/wave/kt: 8 K-frag + 8 V-frag b128 reads only.
// XCD-aware decode: xcd = bid&7 = head h; per-XCD K/V ~2MB < 4MB L2.
// ---------------------------------------------------------------------------
__global__ __launch_bounds__(256, 4) void k_attn(const u16* __restrict__ qkv,
                                                 const u16* __restrict__ vt,
                                                 u16* __restrict__ o) {
    __shared__ u16 smem[16384];              // 32 KB
    // bytes: [0,8K) Ks0 | [8K,16K) Vs0 | [16K,24K) Ks1 | [24K,32K) Vs1
    const int bid = blockIdx.x;
    const int h = bid & 7, sg = bid >> 3;
    const int qt = sg & 15, b = sg >> 4;
    const int q0 = qt << 7;
    const int t = threadIdx.x, lane = t & 63, w = t >> 6;
    const int l31 = lane & 31, hi = lane >> 5;
    const int x7 = l31 & 7;

    char* sb = (char*)smem;
    const char* gk = (const char*)qkv + (size_t)(b << 11) * 3072 + 1024 + h * 128;
    const char* gv = (const char*)vt + (size_t)((b << 3) + h) * 64 * 4096;

    // ---- prologue: prefetch K/V tile 0 into buf0 (drained at first sync) ----
#pragma unroll
    for (int i = 0; i < 2; i++) {
        const int o4 = i * 4096 + t * 16;
        const int row = o4 >> 7;
        const int lc = ((o4 >> 4) & 7) ^ (row & 7);
        gload16(gk + (size_t)row * 3072 + lc * 16, sb + o4);
        gload16(gv + (size_t)row * 4096 + lc * 16, sb + 8192 + o4);
    }

    // ---- Q fragments straight from global (loop-invariant B-frags) ----
    // B-frag 32x32x16: col=q=lane&31, k = ks*16 + hi*8 + j
    bf16x8 qf[4];
    {
        const u16* gqp = qkv + (size_t)((b << 11) + q0 + w * 32 + l31) * 1536 + h * 64 + hi * 8;
#pragma unroll
        for (int ks = 0; ks < 4; ks++)
            qf[ks] = *(const bf16x8*)(gqp + ks * 16);
    }

    f32x16 accO[2];
#pragma unroll
    for (int i = 0; i < 16; i++) { accO[0][i] = 0.f; accO[1][i] = 0.f; }
    float dn = 0.f;

    for (int kt = 0; kt < 32; kt++) {
        const int cur = kt & 1;
        // drains own outstanding staging loads (vmcnt(0)) + barrier:
        // tile kt (issued one iteration ago) is now visible to all waves.
        __syncthreads();
        if (kt < 31) {                       // prefetch tile kt+1 into other buf
            const int kk2 = (kt + 1) << 6;
            char* db = sb + (cur ^ 1) * 16384;
#pragma unroll
            for (int i = 0; i < 2; i++) {
                const int o4 = i * 4096 + t * 16;
                const int row = o4 >> 7;
                const int lc = ((o4 >> 4) & 7) ^ (row & 7);
                gload16(gk + (size_t)(kk2 + row) * 3072 + lc * 16, db + o4);
                gload16(gv + (size_t)row * 4096 + (size_t)kk2 * 2 + lc * 16, db + 8192 + o4);
            }
        }
        const u16* Ksc = smem + cur * 8192;
        const u16* Vsc = Ksc + 4096;

        // S^T = K Q^T  (A = K frag: row=key=lane&31 (+32mt), k=ks*16+hi*8+j)
        f32x16 s2[2];
#pragma unroll
        for (int i = 0; i < 16; i++) { s2[0][i] = 0.f; s2[1][i] = 0.f; }
#pragma unroll
        for (int ks = 0; ks < 4; ks++) {
            const int cx = ((ks * 2 + hi) ^ x7) * 8;
            bf16x8 kf0 = *(const bf16x8*)(Ksc + l31 * 64 + cx);
            bf16x8 kf1 = *(const bf16x8*)(Ksc + (32 + l31) * 64 + cx);
            __builtin_amdgcn_s_setprio(1);
            s2[0] = __builtin_amdgcn_mfma_f32_32x32x16_bf16(kf0, qf[ks], s2[0], 0, 0, 0);
            s2[1] = __builtin_amdgcn_mfma_f32_32x32x16_bf16(kf1, qf[ks], s2[1], 0, 0, 0);
            __builtin_amdgcn_s_setprio(0);
        }

        // p = exp2(s); pack to bf16 pairs; permlane32_swap -> PV B-frags.
        // Source reg r of s2[mt]: key = mt*32 + (r&3) + 8*(r>>2) + 4*hi.
        // pk[c][m] = keys (8c + 4hi + 2m, +1).  For pf[ks=mt*2+ksl]:
        // swap(pk[2ksl][m], pk[2ksl+1][m]) -> res[0]=reg m, res[1]=reg m+2.
        u32 pfu[4][4];
#pragma unroll
        for (int mt = 0; mt < 2; mt++) {
            float pv[16];
#pragma unroll
            for (int r = 0; r < 16; r++) {
                pv[r] = __builtin_amdgcn_exp2f(s2[mt][r]);
                dn += pv[r];
            }
            u32 pk[4][2];
#pragma unroll
            for (int c = 0; c < 4; c++)
#pragma unroll
                for (int m = 0; m < 2; m++)
                    pk[c][m] = pack_trunc(pv[4 * c + 2 * m], pv[4 * c + 2 * m + 1]);
#pragma unroll
            for (int ksl = 0; ksl < 2; ksl++)
#pragma unroll
                for (int m = 0; m < 2; m++) {
                    auto rr = __builtin_amdgcn_permlane32_swap(
                        pk[ksl * 2][m], pk[ksl * 2 + 1][m], false, false);
                    pfu[mt * 2 + ksl][m]     = rr[0];
                    pfu[mt * 2 + ksl][m + 2] = rr[1];
                }
        }

        // O^T += V^T P^T  (A = V^T frag: row=d=lane&31 (+32mtd), k=key)
#pragma unroll
        for (int ks = 0; ks < 4; ks++) {
            u32 pw[4] = {pfu[ks][0], pfu[ks][1], pfu[ks][2], pfu[ks][3]};
            bf16x8 pfv;
            __builtin_memcpy(&pfv, pw, 16);
            const int cx = ((ks * 2 + hi) ^ x7) * 8;
            bf16x8 vf0 = *(const bf16x8*)(Vsc + l31 * 64 + cx);
            bf16x8 vf1 = *(const bf16x8*)(Vsc + (32 + l31) * 64 + cx);
            __builtin_amdgcn_s_setprio(1);
            accO[0] = __builtin_amdgcn_mfma_f32_32x32x16_bf16(vf0, pfv, accO[0], 0, 0, 0);
            accO[1] = __builtin_amdgcn_mfma_f32_32x32x16_bf16(vf1, pfv, accO[1], 0, 0, 0);
            __builtin_amdgcn_s_setprio(0);
        }
    }

    // epilogue: full-row den (hi-half reduce) -> o = accO / den (bf16)
    dn += __shfl_xor(dn, 32, 64);
    const float rdn = __builtin_amdgcn_rcpf(dn);
    const int qg = q0 + w * 32 + l31;
#pragma unroll
    for (int mtd = 0; mtd < 2; mtd++)
#pragma unroll
        for (int g = 0; g < 4; g++) {
            // acc reg 4g+t -> d = mtd*32 + 8g + 4hi + t
            const u32 p0 = (u32)f2bf(accO[mtd][4 * g + 0] * rdn) |
                           ((u32)f2bf(accO[mtd][4 * g + 1] * rdn) << 16);
            const u32 p1 = (u32)f2bf(accO[mtd][4 * g + 2] * rdn) |
                           ((u32)f2bf(accO[mtd][4 * g + 3] * rdn) << 16);
            const int d0 = mtd * 32 + g * 8 + hi * 4;
            *(uint2*)(o + (size_t)((b << 11) + qg) * 512 + h * 64 + d0) =
                make_uint2(p0, p1);
        }
}

// ---------------------------------------------------------------------------
// Host-side pipeline.
// ---------------------------------------------------------------------------
extern "C" void kernel_launch(void* const* d_in, const int* in_sizes, int n_in,
                              void* d_out, int out_size, void* d_ws, size_t ws_size,
                              hipStream_t stream) {
    const float* x      = (const float*)d_in[0];
    const float* ln1_g  = (const float*)d_in[1];
    const float* ln1_b  = (const float*)d_in[2];
    const float* qkv_w  = (const float*)d_in[3];
    const float* qkv_b  = (const float*)d_in[4];
    const float* proj_w = (const float*)d_in[5];
    const float* proj_b = (const float*)d_in[6];
    const float* ln2_g  = (const float*)d_in[7];
    const float* ln2_b  = (const float*)d_in[8];
    const float* fc1_w  = (const float*)d_in[9];
    const float* fc1_b  = (const float*)d_in[10];
    const float* fc2_w  = (const float*)d_in[11];
    const float* fc2_b  = (const float*)d_in[12];
    float* out = (float*)d_out;
    char* ws = (char*)d_ws;

    u16*   qkv_wT = (u16*)(ws + 0);          // 1536x512  bf16
    u16*   proj_wT= (u16*)(ws + 1572864);    // 512x512
    u16*   fc1_wT = (u16*)(ws + 2097152);    // 2048x512
    u16*   fc2_wT = (u16*)(ws + 4194304);    // 512x2048
    u16*   h      = (u16*)(ws + 6291456);    // 8192x512 bf16 (LN outs)
    u16*   qkv    = (u16*)(ws + 14680064);   // 8192x1536
    u16*   vt     = (u16*)(ws + 39845888);   // [b*8+h][64 d][2048 key]
    u16*   o      = (u16*)(ws + 48234496);   // 8192x512 (final attn out, bf16)
    float* x1     = (float*)(ws + 56623104); // 8192x512 fp32
    u16*   f1     = (u16*)(ws + 14680064);   // 8192x2048 (reuse qkv+vt)
    u16*   h2     = h;

    // weights cast+T  +  LN1, one launch
    k_pre<<<5120, 256, 0, stream>>>(qkv_w, qkv_wT, proj_w, proj_wT,
                                    fc1_w, fc1_wT, fc2_w, fc2_wT,
                                    x, ln1_g, ln1_b, h);
    // QKV GEMM; Q cols pre-scaled, V cols -> vt transposed
    k_gemm<3,128><<<(8192/128)*(1536/128), 256, 0, stream>>>(
        h, qkv_wT, qkv_b, nullptr, nullptr, qkv, vt, 8192, 1536, 512);
    // attention (full 2048 keys per block, final o)
    k_attn<<<512, 256, 0, stream>>>(qkv, vt, o);
    // proj GEMM + residual(x) -> x1 fp32
    k_gemm<2,64><<<(8192/128)*(512/64), 256, 0, stream>>>(
        o, proj_wT, proj_b, x, x1, nullptr, nullptr, 8192, 512, 512);
    k_ln<<<2048, 256, 0, stream>>>(x1, ln2_g, ln2_b, h2);
    // FC1 + GELU
    k_gemm<1,128><<<(8192/128)*(2048/128), 256, 0, stream>>>(
        h2, fc1_wT, fc1_b, nullptr, nullptr, f1, nullptr, 8192, 2048, 512);
    // FC2 + residual(x1) -> out fp32
    k_gemm<2,64><<<(8192/128)*(512/64), 256, 0, stream>>>(
        f1, fc2_wT, fc2_b, x1, out, nullptr, nullptr, 8192, 512, 2048);
}

// Round 6
// 226.976 us; speedup vs baseline: 1.2388x; 1.0323x over previous
//
#include <hip/hip_runtime.h>
#include <math.h>

// ---------------------------------------------------------------------------
// TransformerBlock on MI355X (gfx950).  B=4, N=2048, C=512, H=8, D=64.
// All matmuls bf16 MFMA, fp32 accumulate. Residuals fp32.
// R13: k_attn in-block key-split. 8-wave (512-thr) blocks: waves 0-3 do even
//      key-tiles, 4-7 odd (max-free softmax is order-independent). 2 blocks/
//      CU x 8 waves = 16 waves/CU (4/SIMD) -- double R12's 2/SIMD, which was
//      the measured limiter (occ 17%, no pipe >60%, latency-bound). Stages 2
//      tiles per super-iter (32KB), 16 barriers instead of 32. Pair combine
//      (accO+den) via LDS at end -- no combine kernel, no HBM partials.
// ---------------------------------------------------------------------------

using bf16x8 = __attribute__((ext_vector_type(8))) short;
using f32x4  = __attribute__((ext_vector_type(4))) float;
using f32x16 = __attribute__((ext_vector_type(16))) float;

typedef unsigned short u16;
typedef unsigned int   u32;

__device__ __forceinline__ u16 f2bf(float f) {
    u32 u; __builtin_memcpy(&u, &f, 4);
    u32 r = u + 0x7FFFu + ((u >> 16) & 1u);   // RNE
    return (u16)(r >> 16);
}
__device__ __forceinline__ u32 fbits(float f) {
    u32 u; __builtin_memcpy(&u, &f, 4); return u;
}
__device__ __forceinline__ float f_from_bits(u32 u) {
    float f; __builtin_memcpy(&f, &u, 4); return f;
}
// pack two f32 -> two bf16 (truncation) in ONE v_perm_b32
__device__ __forceinline__ u32 pack_trunc(float lo, float hi) {
    return __builtin_amdgcn_perm(fbits(hi), fbits(lo), 0x07060302u);
}
// async global->LDS, 16B per lane; LDS dest = wave-uniform base + lane*16
__device__ __forceinline__ void gload16(const void* g, void* l) {
    __builtin_amdgcn_global_load_lds(
        (const __attribute__((address_space(1))) unsigned int*)g,
        (__attribute__((address_space(3))) unsigned int*)l, 16, 0, 0);
}

// ---------------------------------------------------------------------------
// Fused preprocessing: blocks 0..3071 = weight cast+transpose (4 weights),
// blocks 3072..5119 = LayerNorm1 (fp32 x -> bf16 h).
// ---------------------------------------------------------------------------
__global__ __launch_bounds__(256) void k_pre(
        const float* __restrict__ w0, u16* __restrict__ d0,   // 512x1536
        const float* __restrict__ w1, u16* __restrict__ d1,   // 512x512
        const float* __restrict__ w2, u16* __restrict__ d2,   // 512x2048
        const float* __restrict__ w3, u16* __restrict__ d3,   // 2048x512
        const float* __restrict__ x, const float* __restrict__ g,
        const float* __restrict__ bta, u16* __restrict__ hout) {
    __shared__ float tile[32][33];
    const int bid = blockIdx.x;
    if (bid < 3072) {
        const float* w; u16* dst; int K, N, tb;
        if (bid < 768)       { w = w0; dst = d0; K = 512;  N = 1536; tb = bid; }
        else if (bid < 1024) { w = w1; dst = d1; K = 512;  N = 512;  tb = bid - 768; }
        else if (bid < 2048) { w = w2; dst = d2; K = 512;  N = 2048; tb = bid - 1024; }
        else                 { w = w3; dst = d3; K = 2048; N = 512;  tb = bid - 2048; }
        const int nb = N >> 5;
        const int k0 = (tb / nb) << 5;
        const int n0 = (tb % nb) << 5;
        const int c = threadIdx.x & 31, r = threadIdx.x >> 5;
#pragma unroll
        for (int i = 0; i < 4; i++)
            tile[r + i * 8][c] = w[(size_t)(k0 + r + i * 8) * N + n0 + c];
        __syncthreads();
#pragma unroll
        for (int i = 0; i < 4; i++)
            dst[(size_t)(n0 + r + i * 8) * K + k0 + c] = f2bf(tile[c][r + i * 8]);
    } else {
        const int row  = ((bid - 3072) << 2) + (threadIdx.x >> 6);
        const int lane = threadIdx.x & 63;
        const float* xr = x + (size_t)row * 512 + lane * 8;
        float4 a = *(const float4*)xr;
        float4 c = *(const float4*)(xr + 4);
        float s = a.x + a.y + a.z + a.w + c.x + c.y + c.z + c.w;
        float q = a.x*a.x + a.y*a.y + a.z*a.z + a.w*a.w
                + c.x*c.x + c.y*c.y + c.z*c.z + c.w*c.w;
#pragma unroll
        for (int off = 32; off; off >>= 1) {
            s += __shfl_xor(s, off, 64);
            q += __shfl_xor(q, off, 64);
        }
        const float mean = s * (1.0f / 512.0f);
        const float var  = q * (1.0f / 512.0f) - mean * mean;
        const float rstd = rsqrtf(var + 1e-5f);
        float vv[8] = {a.x, a.y, a.z, a.w, c.x, c.y, c.z, c.w};
#pragma unroll
        for (int j = 0; j < 8; j++) {
            const int col = lane * 8 + j;
            hout[(size_t)row * 512 + col] = f2bf((vv[j] - mean) * rstd * g[col] + bta[col]);
        }
    }
}

// ---------------------------------------------------------------------------
// LayerNorm fp32 -> bf16 (standalone, for LN2).
// ---------------------------------------------------------------------------
__global__ __launch_bounds__(256) void k_ln(const float* __restrict__ x,
                                            const float* __restrict__ g,
                                            const float* __restrict__ bta,
                                            u16* __restrict__ out) {
    const int row  = (blockIdx.x << 2) + (threadIdx.x >> 6);
    const int lane = threadIdx.x & 63;
    const float* xr = x + (size_t)row * 512 + lane * 8;
    float4 a = *(const float4*)xr;
    float4 c = *(const float4*)(xr + 4);
    float s = a.x + a.y + a.z + a.w + c.x + c.y + c.z + c.w;
    float q = a.x*a.x + a.y*a.y + a.z*a.z + a.w*a.w
            + c.x*c.x + c.y*c.y + c.z*c.z + c.w*c.w;
#pragma unroll
    for (int off = 32; off; off >>= 1) {
        s += __shfl_xor(s, off, 64);
        q += __shfl_xor(q, off, 64);
    }
    const float mean = s * (1.0f / 512.0f);
    const float var  = q * (1.0f / 512.0f) - mean * mean;
    const float rstd = rsqrtf(var + 1e-5f);
    float vv[8] = {a.x, a.y, a.z, a.w, c.x, c.y, c.z, c.w};
#pragma unroll
    for (int j = 0; j < 8; j++) {
        const int col = lane * 8 + j;
        out[(size_t)row * 512 + col] = f2bf((vv[j] - mean) * rstd * g[col] + bta[col]);
    }
}

// ---------------------------------------------------------------------------
// GEMM: C[M,N] = A[M,K](bf16) @ Bt[N,K]^T + bias. m97 staging, BK=64,
// 128xTN tile. XCD-grouped decode: xcd = bid&7 owns m-rows m%8==xcd ->
// A-tiles fetched by exactly one XCD; B (<=2MB) L2-resident per XCD.
// EP=1: +tanh-GELU -> bf16.  EP=2: +fp32 residual -> fp32.
// EP=3: QKV — Q cols (<512) pre-scaled by 0.125*log2e, V cols -> vt transposed.
// 8-chunk XOR swizzle (chunk ^= row&7): b128 reads 2-way (free).
// ---------------------------------------------------------------------------
template <int EP, int TN>
__global__ __launch_bounds__(256, 3) void k_gemm(const u16* __restrict__ A,
                                                 const u16* __restrict__ Bt,
                                                 const float* __restrict__ bias,
                                                 const float* __restrict__ res,
                                                 float* __restrict__ outF,
                                                 u16* __restrict__ outB,
                                                 u16* __restrict__ out2,
                                                 int M, int N, int K) {
    constexpr int NT = TN / 32;
    __shared__ u16 As[128 * 64];
    __shared__ u16 Bs[TN * 64];
    const int nb = N / TN;
    // XCD-grouped block decode (grid = (M/128)*nb, M/128 divisible by 8):
    // x = bid&7 -> XCD; within XCD: n fastest (B cycles, L2-resident),
    // m-group slowest (A-tile hot across nb consecutive slots).
    const int xg = blockIdx.x & 7, sg = blockIdx.x >> 3;
    const int m0 = ((sg / nb) * 8 + xg) << 7;
    const int n0 = (sg % nb) * TN;
    const int t = threadIdx.x, lane = t & 63, w = t >> 6;
    const int wr = (w >> 1) << 6;
    const int wc = (w & 1) * (TN / 2);
    const int quad = lane >> 4, l15 = lane & 15;
    const int x7 = l15 & 7;

    f32x4 acc[4][NT];
#pragma unroll
    for (int i = 0; i < 4; i++)
#pragma unroll
        for (int j = 0; j < NT; j++) acc[i][j] = (f32x4){0.f, 0.f, 0.f, 0.f};

    const size_t Kb = (size_t)K * 2;
    const char* ga = (const char*)A + (size_t)m0 * Kb;
    const char* gb = (const char*)Bt + (size_t)n0 * Kb;
    const int o0 = t * 16;

    for (int k0 = 0; k0 < K; k0 += 64) {
        const int kb = k0 * 2;
#pragma unroll
        for (int i = 0; i < 4; i++) {              // A: 128 rows x 128B
            const int o4 = i * 4096 + o0;
            const int row = o4 >> 7;
            const int lc = ((o4 >> 4) & 7) ^ (row & 7);
            gload16(ga + (size_t)row * Kb + kb + lc * 16, (char*)As + o4);
        }
#pragma unroll
        for (int i = 0; i < TN / 32; i++) {        // B: TN rows x 128B
            const int o4 = i * 4096 + o0;
            const int row = o4 >> 7;
            const int lc = ((o4 >> 4) & 7) ^ (row & 7);
            gload16(gb + (size_t)row * Kb + kb + lc * 16, (char*)Bs + o4);
        }
        __syncthreads();
#pragma unroll
        for (int ks = 0; ks < 2; ks++) {
            const int cidx = ((ks * 4 + quad) ^ x7) * 8;
            bf16x8 af[4], bfr[NT];
#pragma unroll
            for (int i = 0; i < 4; i++)
                af[i] = *(const bf16x8*)(As + (wr + i * 16 + l15) * 64 + cidx);
#pragma unroll
            for (int j = 0; j < NT; j++)
                bfr[j] = *(const bf16x8*)(Bs + (wc + j * 16 + l15) * 64 + cidx);
#pragma unroll
            for (int mt = 0; mt < 4; mt++)
#pragma unroll
                for (int nt = 0; nt < NT; nt++)
                    acc[mt][nt] = __builtin_amdgcn_mfma_f32_16x16x32_bf16(
                        af[mt], bfr[nt], acc[mt][nt], 0, 0, 0);
        }
        __syncthreads();
    }

    const bool vpart = (EP == 3) && (n0 >= 1024);          // block-uniform
    const bool qpart = (EP == 3) && (n0 < 512);            // block-uniform
#pragma unroll
    for (int mt = 0; mt < 4; mt++)
#pragma unroll
        for (int nt = 0; nt < NT; nt++) {
            const int col = n0 + wc + nt * 16 + l15;
            const float bi = bias[col];
            const int row0 = m0 + wr + mt * 16 + quad * 4;
            if (vpart) {
                const int b = row0 >> 11, key = row0 & 2047;
                const int hd = col - 1024;          // h*64 + d
                u32 p0 = (u32)f2bf(acc[mt][nt][0] + bi) |
                         ((u32)f2bf(acc[mt][nt][1] + bi) << 16);
                u32 p1 = (u32)f2bf(acc[mt][nt][2] + bi) |
                         ((u32)f2bf(acc[mt][nt][3] + bi) << 16);
                *(uint2*)(out2 + (size_t)(b * 512 + hd) * 2048 + key) = make_uint2(p0, p1);
            } else {
#pragma unroll
                for (int r = 0; r < 4; r++) {
                    const int row = row0 + r;
                    float v = acc[mt][nt][r] + bi;
                    const size_t oi = (size_t)row * N + col;
                    if (EP == 1) {
                        float y = v * (0.79788456f + 0.035677408f * v * v);
                        y = fminf(y, 40.0f);
                        float tE = exp2f(y * 2.88539008f);
                        v = v * tE * __builtin_amdgcn_rcpf(tE + 1.0f);
                    }
                    if (qpart) v *= 0.18033688f;    // 0.125*log2(e) for attn exp2
                    if (EP == 2) outF[oi] = v + res[oi];
                    else         outB[oi] = f2bf(v);
                }
            }
        }
}

// ---------------------------------------------------------------------------
// Flash attention, 32x32x16 MFMA, transposed + max-free, in-block key-split.
// 8 waves (512 thr): wave w -> q-sub (w&3), key parity (w>>2). Per super-iter
// st (16 total): stage tiles {2st, 2st+1} (32KB) double-buffered (64KB LDS);
// one barrier per super-iter. Each wave: QK^T (8 MFMA) -> exp2 + pack +
// permlane32_swap (P in-register) -> PV (8 MFMA) on its parity tile.
// End: pair (w, w+4) combines accO+den via LDS (conflict-free chunk layout),
// waves 0-3 divide and write final o.  16 waves/CU (4/SIMD) at 2 blocks/CU.
// XCD-aware decode: xcd = bid&7 = head h; per-XCD K/V ~2MB < 4MB L2.
// ---------------------------------------------------------------------------
__global__ __launch_bounds__(512, 4) void k_attn(const u16* __restrict__ qkv,
                                                 const u16* __restrict__ vt,
                                                 u16* __restrict__ o) {
    __shared__ u16 smem[32768];              // 64 KB
    // half (32KB): [Ke 8K][Ve 8K][Ko 8K][Vo 8K];  two halves double-buffered
    const int bid = blockIdx.x;
    const int h = bid & 7, sg = bid >> 3;
    const int qt = sg & 15, b = sg >> 4;
    const int q0 = qt << 7;
    const int t = threadIdx.x, lane = t & 63, w = t >> 6;
    const int wq = w & 3, par = w >> 2;
    const int l31 = lane & 31, hi = lane >> 5;
    const int x7 = l31 & 7;

    char* sb = (char*)smem;
    const char* gk = (const char*)qkv + (size_t)(b << 11) * 3072 + 1024 + h * 128;
    const char* gv = (const char*)vt + (size_t)((b << 3) + h) * 64 * 4096;

    // staging geometry: thread t covers byte o4 = t*16 of each 8KB region
    const int o4 = t * 16;
    const int srow = o4 >> 7;                         // 0..63
    const int slc = ((o4 >> 4) & 7) ^ (srow & 7);     // XOR-swizzled chunk

    // ---- prologue: stage super-tile 0 (tiles 0,1) into half 0 ----
    {
        char* db = sb;
        gload16(gk + (size_t)srow * 3072 + slc * 16,            db + o4);            // Ke
        gload16(gv + (size_t)srow * 4096 + slc * 16,            db + 8192 + o4);     // Ve
        gload16(gk + (size_t)(64 + srow) * 3072 + slc * 16,     db + 16384 + o4);    // Ko
        gload16(gv + (size_t)srow * 4096 + 128 + slc * 16,      db + 24576 + o4);    // Vo
    }

    // ---- Q fragments straight from global (loop-invariant B-frags) ----
    // B-frag 32x32x16: col=q=lane&31, k = ks*16 + hi*8 + j
    bf16x8 qf[4];
    {
        const u16* gqp = qkv + (size_t)((b << 11) + q0 + wq * 32 + l31) * 1536 + h * 64 + hi * 8;
#pragma unroll
        for (int ks = 0; ks < 4; ks++)
            qf[ks] = *(const bf16x8*)(gqp + ks * 16);
    }

    f32x16 accO[2];
#pragma unroll
    for (int i = 0; i < 16; i++) { accO[0][i] = 0.f; accO[1][i] = 0.f; }
    float dn = 0.f;

    for (int st = 0; st < 16; st++) {
        const int cur = st & 1;
        // drains own outstanding staging loads (vmcnt(0)) + barrier:
        // super-tile st (issued one iteration ago) is now visible.
        __syncthreads();
        if (st < 15) {                       // prefetch super-tile st+1
            const int kkE = (st + 1) << 7;
            char* db = sb + (cur ^ 1) * 32768;
            gload16(gk + (size_t)(kkE + srow) * 3072 + slc * 16,       db + o4);
            gload16(gv + (size_t)srow * 4096 + (size_t)kkE * 2 + slc * 16, db + 8192 + o4);
            gload16(gk + (size_t)(kkE + 64 + srow) * 3072 + slc * 16,  db + 16384 + o4);
            gload16(gv + (size_t)srow * 4096 + (size_t)(kkE + 64) * 2 + slc * 16, db + 24576 + o4);
        }
        const u16* Ksc = smem + cur * 16384 + par * 8192;
        const u16* Vsc = Ksc + 4096;

        // S^T = K Q^T  (A = K frag: row=key=lane&31 (+32mt), k=ks*16+hi*8+j)
        f32x16 s2[2];
#pragma unroll
        for (int i = 0; i < 16; i++) { s2[0][i] = 0.f; s2[1][i] = 0.f; }
#pragma unroll
        for (int ks = 0; ks < 4; ks++) {
            const int cx = ((ks * 2 + hi) ^ x7) * 8;
            bf16x8 kf0 = *(const bf16x8*)(Ksc + l31 * 64 + cx);
            bf16x8 kf1 = *(const bf16x8*)(Ksc + (32 + l31) * 64 + cx);
            __builtin_amdgcn_s_setprio(1);
            s2[0] = __builtin_amdgcn_mfma_f32_32x32x16_bf16(kf0, qf[ks], s2[0], 0, 0, 0);
            s2[1] = __builtin_amdgcn_mfma_f32_32x32x16_bf16(kf1, qf[ks], s2[1], 0, 0, 0);
            __builtin_amdgcn_s_setprio(0);
        }

        // p = exp2(s); pack to bf16 pairs; permlane32_swap -> PV B-frags.
        // Source reg r of s2[mt]: key = mt*32 + (r&3) + 8*(r>>2) + 4*hi.
        // pk[c][m] = keys (8c + 4hi + 2m, +1).  For pf[ks=mt*2+ksl]:
        // swap(pk[2ksl][m], pk[2ksl+1][m]) -> res[0]=reg m, res[1]=reg m+2.
        u32 pfu[4][4];
#pragma unroll
        for (int mt = 0; mt < 2; mt++) {
            float pv[16];
#pragma unroll
            for (int r = 0; r < 16; r++) {
                pv[r] = __builtin_amdgcn_exp2f(s2[mt][r]);
                dn += pv[r];
            }
            u32 pk[4][2];
#pragma unroll
            for (int c = 0; c < 4; c++)
#pragma unroll
                for (int m = 0; m < 2; m++)
                    pk[c][m] = pack_trunc(pv[4 * c + 2 * m], pv[4 * c + 2 * m + 1]);
#pragma unroll
            for (int ksl = 0; ksl < 2; ksl++)
#pragma unroll
                for (int m = 0; m < 2; m++) {
                    auto rr = __builtin_amdgcn_permlane32_swap(
                        pk[ksl * 2][m], pk[ksl * 2 + 1][m], false, false);
                    pfu[mt * 2 + ksl][m]     = rr[0];
                    pfu[mt * 2 + ksl][m + 2] = rr[1];
                }
        }

        // O^T += V^T P^T  (A = V^T frag: row=d=lane&31 (+32mtd), k=key)
#pragma unroll
        for (int ks = 0; ks < 4; ks++) {
            u32 pw[4] = {pfu[ks][0], pfu[ks][1], pfu[ks][2], pfu[ks][3]};
            bf16x8 pfv;
            __builtin_memcpy(&pfv, pw, 16);
            const int cx = ((ks * 2 + hi) ^ x7) * 8;
            bf16x8 vf0 = *(const bf16x8*)(Vsc + l31 * 64 + cx);
            bf16x8 vf1 = *(const bf16x8*)(Vsc + (32 + l31) * 64 + cx);
            __builtin_amdgcn_s_setprio(1);
            accO[0] = __builtin_amdgcn_mfma_f32_32x32x16_bf16(vf0, pfv, accO[0], 0, 0, 0);
            accO[1] = __builtin_amdgcn_mfma_f32_32x32x16_bf16(vf1, pfv, accO[1], 0, 0, 0);
            __builtin_amdgcn_s_setprio(0);
        }
    }

    // ---- pair combine: waves 4-7 dump accO+den to LDS; waves 0-3 merge ----
    __syncthreads();                          // all reads of staging done
    dn += __shfl_xor(dn, 32, 64);             // intra-wave hi-half reduce
    {
        char* base = sb + wq * 9216;          // 8KB accO + 256B den per pair
        if (par) {
#pragma unroll
            for (int c = 0; c < 8; c++) {
                f32x4 v4;
#pragma unroll
                for (int i = 0; i < 4; i++) v4[i] = accO[c >> 2][(c & 3) * 4 + i];
                *(f32x4*)(base + (c * 64 + lane) * 16) = v4;   // lane-contig
            }
            *(float*)(base + 8192 + lane * 4) = dn;
        }
        __syncthreads();
        if (!par) {
#pragma unroll
            for (int c = 0; c < 8; c++) {
                f32x4 v4 = *(const f32x4*)(base + (c * 64 + lane) * 16);
#pragma unroll
                for (int i = 0; i < 4; i++) accO[c >> 2][(c & 3) * 4 + i] += v4[i];
            }
            dn += *(const float*)(base + 8192 + lane * 4);

            const float rdn = __builtin_amdgcn_rcpf(dn);
            const int qg = q0 + wq * 32 + l31;
#pragma unroll
            for (int mtd = 0; mtd < 2; mtd++)
#pragma unroll
                for (int g = 0; g < 4; g++) {
                    // acc reg 4g+t -> d = mtd*32 + 8g + 4hi + t
                    const u32 p0 = (u32)f2bf(accO[mtd][4 * g + 0] * rdn) |
                                   ((u32)f2bf(accO[mtd][4 * g + 1] * rdn) << 16);
                    const u32 p1 = (u32)f2bf(accO[mtd][4 * g + 2] * rdn) |
                                   ((u32)f2bf(accO[mtd][4 * g + 3] * rdn) << 16);
                    const int d0 = mtd * 32 + g * 8 + hi * 4;
                    *(uint2*)(o + (size_t)((b << 11) + qg) * 512 + h * 64 + d0) =
                        make_uint2(p0, p1);
                }
        }
    }
}

// ---------------------------------------------------------------------------
// Host-side pipeline.
// ---------------------------------------------------------------------------
extern "C" void kernel_launch(void* const* d_in, const int* in_sizes, int n_in,
                              void* d_out, int out_size, void* d_ws, size_t ws_size,
                              hipStream_t stream) {
    const float* x      = (const float*)d_in[0];
    const float* ln1_g  = (const float*)d_in[1];
    const float* ln1_b  = (const float*)d_in[2];
    const float* qkv_w  = (const float*)d_in[3];
    const float* qkv_b  = (const float*)d_in[4];
    const float* proj_w = (const float*)d_in[5];
    const float* proj_b = (const float*)d_in[6];
    const float* ln2_g  = (const float*)d_in[7];
    const float* ln2_b  = (const float*)d_in[8];
    const float* fc1_w  = (const float*)d_in[9];
    const float* fc1_b  = (const float*)d_in[10];
    const float* fc2_w  = (const float*)d_in[11];
    const float* fc2_b  = (const float*)d_in[12];
    float* out = (float*)d_out;
    char* ws = (char*)d_ws;

    u16*   qkv_wT = (u16*)(ws + 0);          // 1536x512  bf16
    u16*   proj_wT= (u16*)(ws + 1572864);    // 512x512
    u16*   fc1_wT = (u16*)(ws + 2097152);    // 2048x512
    u16*   fc2_wT = (u16*)(ws + 4194304);    // 512x2048
    u16*   h      = (u16*)(ws + 6291456);    // 8192x512 bf16 (LN outs)
    u16*   qkv    = (u16*)(ws + 14680064);   // 8192x1536
    u16*   vt     = (u16*)(ws + 39845888);   // [b*8+h][64 d][2048 key]
    u16*   o      = (u16*)(ws + 48234496);   // 8192x512 (final attn out, bf16)
    float* x1     = (float*)(ws + 56623104); // 8192x512 fp32
    u16*   f1     = (u16*)(ws + 14680064);   // 8192x2048 (reuse qkv+vt)
    u16*   h2     = h;

    // weights cast+T  +  LN1, one launch
    k_pre<<<5120, 256, 0, stream>>>(qkv_w, qkv_wT, proj_w, proj_wT,
                                    fc1_w, fc1_wT, fc2_w, fc2_wT,
                                    x, ln1_g, ln1_b, h);
    // QKV GEMM; Q cols pre-scaled, V cols -> vt transposed
    k_gemm<3,128><<<(8192/128)*(1536/128), 256, 0, stream>>>(
        h, qkv_wT, qkv_b, nullptr, nullptr, qkv, vt, 8192, 1536, 512);
    // attention (in-block key-split, full 2048 keys, final o)
    k_attn<<<512, 512, 0, stream>>>(qkv, vt, o);
    // proj GEMM + residual(x) -> x1 fp32
    k_gemm<2,64><<<(8192/128)*(512/64), 256, 0, stream>>>(
        o, proj_wT, proj_b, x, x1, nullptr, nullptr, 8192, 512, 512);
    k_ln<<<2048, 256, 0, stream>>>(x1, ln2_g, ln2_b, h2);
    // FC1 + GELU
    k_gemm<1,128><<<(8192/128)*(2048/128), 256, 0, stream>>>(
        h2, fc1_wT, fc1_b, nullptr, nullptr, f1, nullptr, 8192, 2048, 512);
    // FC2 + residual(x1) -> out fp32
    k_gemm<2,64><<<(8192/128)*(512/64), 256, 0, stream>>>(
        f1, fc2_wT, fc2_b, x1, out, nullptr, nullptr, 8192, 512, 2048);
}